// Round 1
// baseline (4325.104 us; speedup 1.0000x reference)
//
#include <hip/hip_runtime.h>
#include <hip/hip_bf16.h>

// ---------------------------------------------------------------------------
// GCN forward, 2 layers. All fp32.
// Stage 1: support1 = feature @ W1              (gemm_f32)
// Stage 2: agg1[dst] += support1[src]*w  (atomics into d_out x1 slot)
// Stage 3: x1 = relu(agg1 + b1)                 (in place on d_out)
// Stage 4: support2 = x1 @ W2                   (gemm_f32)
// Stage 5: agg2[dst] += support2[src]*w  (atomics into d_out x2 slot)
// Stage 6: out2 = log_softmax(agg2 + b2)        (in place, one wave per row)
// Workspace: support1 (N*H floats) + support2 (N*D floats) = 76.8 MB.
// ---------------------------------------------------------------------------

#define BM 64
#define BN 64
#define BK 16

// Classic LDS-tiled fp32 GEMM: C[M,Ncols] = A[M,K] @ B[K,Ncols].
// Requires K % 16 == 0, Ncols % 64 == 0 (true here: K in {256,128}, Ncols in {128,64}).
__global__ __launch_bounds__(256) void gemm_f32(
    const float* __restrict__ A, const float* __restrict__ B,
    float* __restrict__ C, int M, int K, int Ncols)
{
    __shared__ float As[BK][BM];   // A tile, transposed: As[k][row]
    __shared__ float Bs[BK][BN];

    const int tid = threadIdx.x;
    const int tx = tid & 15;        // col group 0..15
    const int ty = tid >> 4;        // row group 0..15
    const int row0 = blockIdx.x * BM;
    const int col0 = blockIdx.y * BN;

    const int aRow = tid >> 2;      // 0..63
    const int aSeg = tid & 3;       // 0..3  (4 floats each)
    const int bRow = tid >> 4;      // 0..15
    const int bCol = tid & 15;      // 0..15 (4 floats each)

    float acc[4][4] = {};

    for (int k0 = 0; k0 < K; k0 += BK) {
        float4 av = make_float4(0.f, 0.f, 0.f, 0.f);
        const int ar = row0 + aRow;
        if (ar < M)
            av = *(const float4*)&A[(size_t)ar * K + k0 + aSeg * 4];
        const float4 bv = *(const float4*)&B[(size_t)(k0 + bRow) * Ncols + col0 + bCol * 4];

        __syncthreads();
        As[aSeg * 4 + 0][aRow] = av.x;
        As[aSeg * 4 + 1][aRow] = av.y;
        As[aSeg * 4 + 2][aRow] = av.z;
        As[aSeg * 4 + 3][aRow] = av.w;
        *(float4*)&Bs[bRow][bCol * 4] = bv;
        __syncthreads();

#pragma unroll
        for (int kk = 0; kk < BK; ++kk) {
            const float4 a4 = *(const float4*)&As[kk][ty * 4];
            const float4 b4 = *(const float4*)&Bs[kk][tx * 4];
            const float a[4] = {a4.x, a4.y, a4.z, a4.w};
            const float b[4] = {b4.x, b4.y, b4.z, b4.w};
#pragma unroll
            for (int i = 0; i < 4; ++i)
#pragma unroll
                for (int j = 0; j < 4; ++j)
                    acc[i][j] = fmaf(a[i], b[j], acc[i][j]);
        }
    }

#pragma unroll
    for (int i = 0; i < 4; ++i) {
        const int r = row0 + ty * 4 + i;
        if (r < M) {
            const float4 o = make_float4(acc[i][0], acc[i][1], acc[i][2], acc[i][3]);
            *(float4*)&C[(size_t)r * Ncols + col0 + tx * 4] = o;
        }
    }
}

// Edge scatter: agg[dst[e]] += sup[src[e]] * ew[e].  F/4 lanes per edge,
// float4 per lane; hardware fp32 global atomics (device scope).
template <int F>
__global__ __launch_bounds__(256) void scatter_add(
    const float* __restrict__ sup, const int* __restrict__ src,
    const int* __restrict__ dst, const float* __restrict__ ew,
    float* __restrict__ agg, int E)
{
    constexpr int LPE = F / 4;
    const long long t = (long long)blockIdx.x * blockDim.x + threadIdx.x;
    const int e = (int)(t / LPE);
    const int l = (int)(t % LPE);
    if (e >= E) return;

    const int s = src[e];
    const int d = dst[e];
    const float w = ew[e];

    const float4 v = *(const float4*)&sup[(size_t)s * F + l * 4];
    float* out = &agg[(size_t)d * F + l * 4];
    unsafeAtomicAdd(out + 0, v.x * w);
    unsafeAtomicAdd(out + 1, v.y * w);
    unsafeAtomicAdd(out + 2, v.z * w);
    unsafeAtomicAdd(out + 3, v.w * w);
}

// x = relu(x + b[f]) elementwise, float4 vectorized. total4 = N*F/4.
__global__ __launch_bounds__(256) void bias_relu(
    float* __restrict__ x, const float* __restrict__ b, long long total4, int F)
{
    const long long i = (long long)blockIdx.x * blockDim.x + threadIdx.x;
    if (i >= total4) return;
    const int f0 = (int)((i * 4) % F);
    float4 v = *(float4*)&x[i * 4];
    v.x = fmaxf(v.x + b[f0 + 0], 0.f);
    v.y = fmaxf(v.y + b[f0 + 1], 0.f);
    v.z = fmaxf(v.z + b[f0 + 2], 0.f);
    v.w = fmaxf(v.w + b[f0 + 3], 0.f);
    *(float4*)&x[i * 4] = v;
}

// log_softmax over rows of 64, one wave per row, in place: x = (x+b) - m - log(sum exp)
__global__ __launch_bounds__(256) void logsoftmax64(
    float* __restrict__ x, const float* __restrict__ b, int N)
{
    const int wave = (blockIdx.x * blockDim.x + threadIdx.x) >> 6;
    const int lane = threadIdx.x & 63;
    if (wave >= N) return;

    const float z = x[(size_t)wave * 64 + lane] + b[lane];
    float m = z;
#pragma unroll
    for (int o = 32; o > 0; o >>= 1) m = fmaxf(m, __shfl_xor(m, o, 64));
    const float ex = __expf(z - m);
    float s = ex;
#pragma unroll
    for (int o = 32; o > 0; o >>= 1) s += __shfl_xor(s, o, 64);
    x[(size_t)wave * 64 + lane] = z - m - __logf(s);
}

extern "C" void kernel_launch(void* const* d_in, const int* in_sizes, int n_in,
                              void* d_out, int out_size, void* d_ws, size_t ws_size,
                              hipStream_t stream) {
    const float* feature = (const float*)d_in[0];
    const int*   src     = (const int*)d_in[1];
    const int*   dst     = (const int*)d_in[2];
    const float* ew      = (const float*)d_in[3];
    const float* W1      = (const float*)d_in[4];
    const float* b1      = (const float*)d_in[5];
    const float* W2      = (const float*)d_in[6];
    const float* b2      = (const float*)d_in[7];

    const int E    = in_sizes[1];
    const int H    = in_sizes[5];            // 128
    const int D    = in_sizes[7];            // 64
    const int F_IN = in_sizes[4] / H;        // 256
    const int N    = in_sizes[0] / F_IN;     // 100000

    float* out_x1 = (float*)d_out;                       // [N, H]
    float* out_x2 = (float*)d_out + (size_t)N * H;       // [N, D]

    float* support1 = (float*)d_ws;                      // [N, H]
    float* support2 = (float*)d_ws + (size_t)N * H;      // [N, D]

    // Zero the accumulation targets (harness poisons d_out with 0xAA).
    hipMemsetAsync(d_out, 0, (size_t)out_size * sizeof(float), stream);

    // --- Layer 1 ---
    {
        dim3 grid((N + BM - 1) / BM, H / BN);
        gemm_f32<<<grid, 256, 0, stream>>>(feature, W1, support1, N, F_IN, H);
    }
    {
        const long long threads = (long long)E * (H / 4);
        const int blocks = (int)((threads + 255) / 256);
        scatter_add<128><<<blocks, 256, 0, stream>>>(support1, src, dst, ew, out_x1, E);
    }
    {
        const long long total4 = (long long)N * H / 4;
        const int blocks = (int)((total4 + 255) / 256);
        bias_relu<<<blocks, 256, 0, stream>>>(out_x1, b1, total4, H);
    }

    // --- Layer 2 ---
    {
        dim3 grid((N + BM - 1) / BM, D / BN);
        gemm_f32<<<grid, 256, 0, stream>>>(out_x1, W2, support2, N, H, D);
    }
    {
        const long long threads = (long long)E * (D / 4);
        const int blocks = (int)((threads + 255) / 256);
        scatter_add<64><<<blocks, 256, 0, stream>>>(support2, src, dst, ew, out_x2, E);
    }
    {
        const int rows_per_block = 256 / 64;
        const int blocks = (N + rows_per_block - 1) / rows_per_block;
        logsoftmax64<<<blocks, 256, 0, stream>>>(out_x2, b2, N);
    }
}

// Round 2
// 697.724 us; speedup vs baseline: 6.1989x; 6.1989x over previous
//
#include <hip/hip_runtime.h>
#include <hip/hip_bf16.h>

// ---------------------------------------------------------------------------
// GCN forward, 2 layers, fp32. Round 2: replace atomic scatter with on-the-fly
// dst-CSR build + gather-side aggregation (no float atomics at all).
//
//  1. support1 = feature @ W1                      gemm_f32
//  2. counts[dst]++                                histogram
//  3. offs = exclusive_scan(counts)                scan_pass1/2/3 (also fills cursor)
//  4. CSR reorder: esrc/ewgt sorted by dst         reorder
//  5. x1 = relu(sum_j w_j*support1[src_j] + b1)    agg_f128 (one wave / node)
//  6. support2 = x1 @ W2                           gemm_f32
//  7. out2 = log_softmax(sum + b2)                 agg_f64_lsm (one wave / node)
//
// Workspace layout (≈65 MB): counts[N], offs[N+1], cursor[N], blockSums,
// esrc[E], ewgt[E], support (max(N*128) floats, reused for support2).
// ---------------------------------------------------------------------------

#define BM 64
#define BN 64
#define BK 16

__global__ __launch_bounds__(256) void gemm_f32(
    const float* __restrict__ A, const float* __restrict__ B,
    float* __restrict__ C, int M, int K, int Ncols)
{
    __shared__ float As[BK][BM];
    __shared__ float Bs[BK][BN];

    const int tid = threadIdx.x;
    const int tx = tid & 15;
    const int ty = tid >> 4;
    const int row0 = blockIdx.x * BM;
    const int col0 = blockIdx.y * BN;

    const int aRow = tid >> 2;
    const int aSeg = tid & 3;
    const int bRow = tid >> 4;
    const int bCol = tid & 15;

    float acc[4][4] = {};

    for (int k0 = 0; k0 < K; k0 += BK) {
        float4 av = make_float4(0.f, 0.f, 0.f, 0.f);
        const int ar = row0 + aRow;
        if (ar < M)
            av = *(const float4*)&A[(size_t)ar * K + k0 + aSeg * 4];
        const float4 bv = *(const float4*)&B[(size_t)(k0 + bRow) * Ncols + col0 + bCol * 4];

        __syncthreads();
        As[aSeg * 4 + 0][aRow] = av.x;
        As[aSeg * 4 + 1][aRow] = av.y;
        As[aSeg * 4 + 2][aRow] = av.z;
        As[aSeg * 4 + 3][aRow] = av.w;
        *(float4*)&Bs[bRow][bCol * 4] = bv;
        __syncthreads();

#pragma unroll
        for (int kk = 0; kk < BK; ++kk) {
            const float4 a4 = *(const float4*)&As[kk][ty * 4];
            const float4 b4 = *(const float4*)&Bs[kk][tx * 4];
            const float a[4] = {a4.x, a4.y, a4.z, a4.w};
            const float b[4] = {b4.x, b4.y, b4.z, b4.w};
#pragma unroll
            for (int i = 0; i < 4; ++i)
#pragma unroll
                for (int j = 0; j < 4; ++j)
                    acc[i][j] = fmaf(a[i], b[j], acc[i][j]);
        }
    }

#pragma unroll
    for (int i = 0; i < 4; ++i) {
        const int r = row0 + ty * 4 + i;
        if (r < M) {
            const float4 o = make_float4(acc[i][0], acc[i][1], acc[i][2], acc[i][3]);
            *(float4*)&C[(size_t)r * Ncols + col0 + tx * 4] = o;
        }
    }
}

// ---------------- CSR build ----------------

__global__ __launch_bounds__(256) void histogram_k(
    const int* __restrict__ dst, int* __restrict__ counts, int E)
{
    const int e = blockIdx.x * blockDim.x + threadIdx.x;
    if (e < E) atomicAdd(&counts[dst[e]], 1);
}

#define SCAN_B 256
#define SCAN_I 8
#define SCAN_TILE (SCAN_B * SCAN_I)   // 2048

__global__ __launch_bounds__(SCAN_B) void scan_pass1(
    const int* __restrict__ in, int* __restrict__ out,
    int* __restrict__ blockSums, int n)
{
    __shared__ int waveSums[SCAN_B / 64];
    const int tid = threadIdx.x;
    const int lane = tid & 63;
    const int wid = tid >> 6;
    const int base = blockIdx.x * SCAN_TILE + tid * SCAN_I;

    int items[SCAN_I];
    int tsum = 0;
#pragma unroll
    for (int i = 0; i < SCAN_I; ++i) {
        const int idx = base + i;
        items[i] = (idx < n) ? in[idx] : 0;
        tsum += items[i];
    }
    // inclusive wave scan of tsum
    int x = tsum;
#pragma unroll
    for (int o = 1; o < 64; o <<= 1) {
        const int y = __shfl_up(x, o, 64);
        if (lane >= o) x += y;
    }
    if (lane == 63) waveSums[wid] = x;
    __syncthreads();
    if (tid == 0) {
        int acc = 0;
#pragma unroll
        for (int w = 0; w < SCAN_B / 64; ++w) {
            const int t = waveSums[w]; waveSums[w] = acc; acc += t;
        }
        blockSums[blockIdx.x] = acc;
    }
    __syncthreads();
    int texcl = x - tsum + waveSums[wid];
#pragma unroll
    for (int i = 0; i < SCAN_I; ++i) {
        const int idx = base + i;
        if (idx < n) out[idx] = texcl;
        texcl += items[i];
    }
}

// single-wave scan of blockSums (nb small: ceil(100000/2048)=49)
__global__ void scan_pass2(int* __restrict__ blockSums, int nb)
{
    const int lane = threadIdx.x;
    int run = 0;
    for (int base = 0; base < nb; base += 64) {
        const int idx = base + lane;
        const int v = (idx < nb) ? blockSums[idx] : 0;
        int x = v;
#pragma unroll
        for (int o = 1; o < 64; o <<= 1) {
            const int y = __shfl_up(x, o, 64);
            if (lane >= o) x += y;
        }
        if (idx < nb) blockSums[idx] = run + x - v;   // exclusive
        run += __shfl(x, 63, 64);
    }
}

__global__ __launch_bounds__(SCAN_B) void scan_pass3(
    int* __restrict__ offs, int* __restrict__ cursor,
    const int* __restrict__ blockSums, int n, int total)
{
    const int idx = blockIdx.x * blockDim.x + threadIdx.x;
    if (idx < n) {
        const int v = offs[idx] + blockSums[idx / SCAN_TILE];
        offs[idx] = v;
        cursor[idx] = v;
    }
    if (idx == n) offs[n] = total;
}

__global__ __launch_bounds__(256) void reorder_k(
    const int* __restrict__ src, const int* __restrict__ dst,
    const float* __restrict__ ew, int* __restrict__ cursor,
    int* __restrict__ esrc, float* __restrict__ ewgt, int E)
{
    const int e = blockIdx.x * blockDim.x + threadIdx.x;
    if (e >= E) return;
    const int p = atomicAdd(&cursor[dst[e]], 1);
    esrc[p] = src[e];
    ewgt[p] = ew[e];
}

// ---------------- gather-side aggregation ----------------

// F=128: one wave per node, float2 per lane; fused bias + relu.
__global__ __launch_bounds__(256) void agg_f128(
    const float* __restrict__ sup, const int* __restrict__ offs,
    const int* __restrict__ esrc, const float* __restrict__ ewgt,
    const float* __restrict__ bias, float* __restrict__ out, int N)
{
    const int wave = (blockIdx.x * blockDim.x + threadIdx.x) >> 6;
    const int lane = threadIdx.x & 63;
    if (wave >= N) return;

    const int beg = offs[wave];
    const int end = offs[wave + 1];

    float2 a0 = {0.f, 0.f}, a1 = {0.f, 0.f};
    int j = beg;
    for (; j + 1 < end; j += 2) {
        const int s0 = esrc[j];
        const int s1 = esrc[j + 1];
        const float w0 = ewgt[j];
        const float w1 = ewgt[j + 1];
        const float2 v0 = *(const float2*)&sup[(size_t)s0 * 128 + lane * 2];
        const float2 v1 = *(const float2*)&sup[(size_t)s1 * 128 + lane * 2];
        a0.x = fmaf(v0.x, w0, a0.x); a0.y = fmaf(v0.y, w0, a0.y);
        a1.x = fmaf(v1.x, w1, a1.x); a1.y = fmaf(v1.y, w1, a1.y);
    }
    if (j < end) {
        const int s0 = esrc[j];
        const float w0 = ewgt[j];
        const float2 v0 = *(const float2*)&sup[(size_t)s0 * 128 + lane * 2];
        a0.x = fmaf(v0.x, w0, a0.x); a0.y = fmaf(v0.y, w0, a0.y);
    }
    const float2 b = *(const float2*)&bias[lane * 2];
    float2 o;
    o.x = fmaxf(a0.x + a1.x + b.x, 0.f);
    o.y = fmaxf(a0.y + a1.y + b.y, 0.f);
    *(float2*)&out[(size_t)wave * 128 + lane * 2] = o;
}

// F=64: one wave per node, 1 float per lane; fused bias + log_softmax.
__global__ __launch_bounds__(256) void agg_f64_lsm(
    const float* __restrict__ sup, const int* __restrict__ offs,
    const int* __restrict__ esrc, const float* __restrict__ ewgt,
    const float* __restrict__ bias, float* __restrict__ out, int N)
{
    const int wave = (blockIdx.x * blockDim.x + threadIdx.x) >> 6;
    const int lane = threadIdx.x & 63;
    if (wave >= N) return;

    const int beg = offs[wave];
    const int end = offs[wave + 1];

    float a0 = 0.f, a1 = 0.f;
    int j = beg;
    for (; j + 1 < end; j += 2) {
        const int s0 = esrc[j];
        const int s1 = esrc[j + 1];
        const float w0 = ewgt[j];
        const float w1 = ewgt[j + 1];
        a0 = fmaf(sup[(size_t)s0 * 64 + lane], w0, a0);
        a1 = fmaf(sup[(size_t)s1 * 64 + lane], w1, a1);
    }
    if (j < end)
        a0 = fmaf(sup[(size_t)esrc[j] * 64 + lane], ewgt[j], a0);

    const float z = a0 + a1 + bias[lane];
    float m = z;
#pragma unroll
    for (int o = 32; o > 0; o >>= 1) m = fmaxf(m, __shfl_xor(m, o, 64));
    const float ex = __expf(z - m);
    float s = ex;
#pragma unroll
    for (int o = 32; o > 0; o >>= 1) s += __shfl_xor(s, o, 64);
    out[(size_t)wave * 64 + lane] = z - m - __logf(s);
}

// ---------------------------------------------------------------------------

extern "C" void kernel_launch(void* const* d_in, const int* in_sizes, int n_in,
                              void* d_out, int out_size, void* d_ws, size_t ws_size,
                              hipStream_t stream) {
    const float* feature = (const float*)d_in[0];
    const int*   src     = (const int*)d_in[1];
    const int*   dst     = (const int*)d_in[2];
    const float* ew      = (const float*)d_in[3];
    const float* W1      = (const float*)d_in[4];
    const float* b1      = (const float*)d_in[5];
    const float* W2      = (const float*)d_in[6];
    const float* b2      = (const float*)d_in[7];

    const int E    = in_sizes[1];
    const int H    = in_sizes[5];            // 128
    const int D    = in_sizes[7];            // 64
    const int F_IN = in_sizes[4] / H;        // 256
    const int N    = in_sizes[0] / F_IN;     // 100000

    float* out_x1 = (float*)d_out;                   // [N, H]
    float* out_x2 = (float*)d_out + (size_t)N * H;   // [N, D]

    // --- workspace carve-up (16B aligned) ---
    char* ws = (char*)d_ws;
    auto carve = [&](size_t bytes) {
        char* p = ws;
        ws += (bytes + 15) & ~(size_t)15;
        return p;
    };
    int*   counts    = (int*)  carve((size_t)N * sizeof(int));
    int*   offs      = (int*)  carve((size_t)(N + 1) * sizeof(int));
    int*   cursor    = (int*)  carve((size_t)N * sizeof(int));
    int*   blockSums = (int*)  carve(4096 * sizeof(int));
    int*   esrc      = (int*)  carve((size_t)E * sizeof(int));
    float* ewgt      = (float*)carve((size_t)E * sizeof(float));
    float* support   = (float*)carve((size_t)N * H * sizeof(float)); // reused for layer 2

    // --- CSR build (independent of GEMM1; ordered on stream) ---
    hipMemsetAsync(counts, 0, (size_t)N * sizeof(int), stream);
    histogram_k<<<(E + 255) / 256, 256, 0, stream>>>(dst, counts, E);
    const int nScanBlocks = (N + SCAN_TILE - 1) / SCAN_TILE;
    scan_pass1<<<nScanBlocks, SCAN_B, 0, stream>>>(counts, offs, blockSums, N);
    scan_pass2<<<1, 64, 0, stream>>>(blockSums, nScanBlocks);
    scan_pass3<<<(N + 1 + SCAN_B - 1) / SCAN_B, SCAN_B, 0, stream>>>(offs, cursor, blockSums, N, E);
    reorder_k<<<(E + 255) / 256, 256, 0, stream>>>(src, dst, ew, cursor, esrc, ewgt, E);

    // --- Layer 1 ---
    {
        dim3 grid((N + BM - 1) / BM, H / BN);
        gemm_f32<<<grid, 256, 0, stream>>>(feature, W1, support, N, F_IN, H);
    }
    agg_f128<<<(N * 64 + 255) / 256, 256, 0, stream>>>(support, offs, esrc, ewgt, b1, out_x1, N);

    // --- Layer 2 ---
    {
        dim3 grid((N + BM - 1) / BM, D / BN);
        gemm_f32<<<grid, 256, 0, stream>>>(out_x1, W2, support, N, H, D);
    }
    agg_f64_lsm<<<(N * 64 + 255) / 256, 256, 0, stream>>>(support, offs, esrc, ewgt, b2, out_x2, N);
}

// Round 3
// 598.930 us; speedup vs baseline: 7.2214x; 1.1650x over previous
//
#include <hip/hip_runtime.h>
#include <hip/hip_bf16.h>
#include <type_traits>

// ---------------------------------------------------------------------------
// GCN forward, 2 layers. Round 3: bf16 MFMA GEMMs + bf16 gather payloads.
//
//  CSR build (histogram/scan/reorder) -> dst-sorted edge list   (unchanged)
//  prep: W1^T, W2^T cast to bf16
//  gemm_mfma<float,128>: sup1bf = bf16(feature) @ W1   (fp32 A cast inline)
//  agg_f128b: x1 = relu(sum w*sup1bf[src] + b1) -> fp32 out + bf16 copy
//  gemm_mfma<u16,64>:    sup2bf = x1bf @ W2
//  agg_f64_lsm: out2 = log_softmax(sum w*sup2bf[src] + b2)
// ---------------------------------------------------------------------------

typedef unsigned short u16;

__device__ __forceinline__ u16 f2bf(float x) {
    union { float f; unsigned u; } v; v.f = x;
    const unsigned r = v.u + 0x7FFFu + ((v.u >> 16) & 1u);   // RNE
    return (u16)(r >> 16);
}
__device__ __forceinline__ float bf2f(unsigned h) {
    union { unsigned u; float f; } v; v.u = h << 16;
    return v.f;
}

using short8  = __attribute__((ext_vector_type(8))) short;
using float4v = __attribute__((ext_vector_type(4))) float;

// ---------------- MFMA GEMM: C[M,BNt](bf16) = A[M,K] @ BT[BNt,K]^T ----------
// BMt=128, BK=32. 4 waves. BNt=128: 2x2 waves of 64x64. BNt=64: 4x1 of 32x64.
// AT=float: A is fp32, cast to bf16 during LDS staging. AT=u16: A already bf16.
template <typename AT, int BNt>
__global__ __launch_bounds__(256) void gemm_mfma(
    const AT* __restrict__ A, const u16* __restrict__ BT,
    u16* __restrict__ C, int M, int K)
{
    constexpr int BMt = 128;
    constexpr int WAVES_N = BNt / 64;
    constexpr int WROWS = 4 / WAVES_N;
    constexpr int WMF = BMt / (16 * WROWS);   // m-frags per wave
    constexpr int WNF = 4;                    // n-frags per wave (64 cols)

    __shared__ __align__(16) u16 As[BMt * 32];   // [m][k]
    __shared__ __align__(16) u16 Bs[BNt * 32];   // [n][k]

    const int tid  = threadIdx.x;
    const int lane = tid & 63;
    const int w    = tid >> 6;
    const int m0   = blockIdx.x * BMt;

    const int wm = (w % WROWS) * (WMF * 16);
    const int wn = (w / WROWS) * 64;

    const int fm = lane & 15;     // fragment row/col within 16
    const int kh = lane >> 4;     // k-quarter 0..3

    float4v acc[WMF][WNF] = {};

    for (int k0 = 0; k0 < K; k0 += 32) {
        __syncthreads();
        // ---- stage A tile [128 x 32] ----
        if constexpr (std::is_same<AT, float>::value) {
#pragma unroll
            for (int i = 0; i < 4; ++i) {
                const int s   = i * 256 + tid;     // 0..1023
                const int row = s >> 3;            // 0..127
                const int seg = s & 7;             // 4 floats each
                const int gr  = min(m0 + row, M - 1);
                const float4 v = *(const float4*)&A[(size_t)gr * K + k0 + seg * 4];
                ushort4 o;
                o.x = f2bf(v.x); o.y = f2bf(v.y); o.z = f2bf(v.z); o.w = f2bf(v.w);
                *(ushort4*)&As[row * 32 + seg * 4] = o;
            }
        } else {
#pragma unroll
            for (int i = 0; i < 2; ++i) {
                const int s   = i * 256 + tid;     // 0..511
                const int row = s >> 2;
                const int seg = s & 3;             // 8 bf16 each
                const int gr  = min(m0 + row, M - 1);
                *(uint4*)&As[row * 32 + seg * 8] =
                    *(const uint4*)&A[(size_t)gr * K + k0 + seg * 8];
            }
        }
        // ---- stage B tile [BNt x 32] from BT[BNt,K] ----
#pragma unroll
        for (int i = 0; i < BNt * 4 / 256; ++i) {
            const int s   = i * 256 + tid;
            const int row = s >> 2;
            const int seg = s & 3;
            *(uint4*)&Bs[row * 32 + seg * 8] =
                *(const uint4*)&BT[(size_t)row * K + k0 + seg * 8];
        }
        __syncthreads();

        short8 af[WMF], bfr[WNF];
#pragma unroll
        for (int i = 0; i < WMF; ++i)
            af[i] = *(const short8*)&As[(wm + i * 16 + fm) * 32 + kh * 8];
#pragma unroll
        for (int j = 0; j < WNF; ++j)
            bfr[j] = *(const short8*)&Bs[(wn + j * 16 + fm) * 32 + kh * 8];
#pragma unroll
        for (int i = 0; i < WMF; ++i)
#pragma unroll
            for (int j = 0; j < WNF; ++j)
                acc[i][j] = __builtin_amdgcn_mfma_f32_16x16x32_bf16(
                    af[i], bfr[j], acc[i][j], 0, 0, 0);
    }

    // ---- epilogue: C/D layout col=lane&15, row=(lane>>4)*4+reg ----
#pragma unroll
    for (int i = 0; i < WMF; ++i) {
#pragma unroll
        for (int j = 0; j < WNF; ++j) {
            const int col = wn + j * 16 + fm;
#pragma unroll
            for (int r = 0; r < 4; ++r) {
                const int row = m0 + wm + i * 16 + kh * 4 + r;
                if (row < M) C[(size_t)row * BNt + col] = f2bf(acc[i][j][r]);
            }
        }
    }
}

// Tiny: WT[n][k] = bf16(W[k][n])
__global__ __launch_bounds__(256) void transpose_cast(
    const float* __restrict__ W, u16* __restrict__ WT, int K, int Ncols)
{
    const int t = blockIdx.x * blockDim.x + threadIdx.x;
    if (t >= K * Ncols) return;
    const int k = t % K, n = t / K;
    WT[(size_t)n * K + k] = f2bf(W[(size_t)k * Ncols + n]);
}

// ---------------- CSR build ----------------

__global__ __launch_bounds__(256) void histogram_k(
    const int* __restrict__ dst, int* __restrict__ counts, int E)
{
    const int e = blockIdx.x * blockDim.x + threadIdx.x;
    if (e < E) atomicAdd(&counts[dst[e]], 1);
}

#define SCAN_B 256
#define SCAN_I 8
#define SCAN_TILE (SCAN_B * SCAN_I)   // 2048

__global__ __launch_bounds__(SCAN_B) void scan_pass1(
    const int* __restrict__ in, int* __restrict__ out,
    int* __restrict__ blockSums, int n)
{
    __shared__ int waveSums[SCAN_B / 64];
    const int tid = threadIdx.x;
    const int lane = tid & 63;
    const int wid = tid >> 6;
    const int base = blockIdx.x * SCAN_TILE + tid * SCAN_I;

    int items[SCAN_I];
    int tsum = 0;
#pragma unroll
    for (int i = 0; i < SCAN_I; ++i) {
        const int idx = base + i;
        items[i] = (idx < n) ? in[idx] : 0;
        tsum += items[i];
    }
    int x = tsum;
#pragma unroll
    for (int o = 1; o < 64; o <<= 1) {
        const int y = __shfl_up(x, o, 64);
        if (lane >= o) x += y;
    }
    if (lane == 63) waveSums[wid] = x;
    __syncthreads();
    if (tid == 0) {
        int acc = 0;
#pragma unroll
        for (int w = 0; w < SCAN_B / 64; ++w) {
            const int t = waveSums[w]; waveSums[w] = acc; acc += t;
        }
        blockSums[blockIdx.x] = acc;
    }
    __syncthreads();
    int texcl = x - tsum + waveSums[wid];
#pragma unroll
    for (int i = 0; i < SCAN_I; ++i) {
        const int idx = base + i;
        if (idx < n) out[idx] = texcl;
        texcl += items[i];
    }
}

__global__ void scan_pass2(int* __restrict__ blockSums, int nb)
{
    const int lane = threadIdx.x;
    int run = 0;
    for (int base = 0; base < nb; base += 64) {
        const int idx = base + lane;
        const int v = (idx < nb) ? blockSums[idx] : 0;
        int x = v;
#pragma unroll
        for (int o = 1; o < 64; o <<= 1) {
            const int y = __shfl_up(x, o, 64);
            if (lane >= o) x += y;
        }
        if (idx < nb) blockSums[idx] = run + x - v;
        run += __shfl(x, 63, 64);
    }
}

__global__ __launch_bounds__(SCAN_B) void scan_pass3(
    int* __restrict__ offs, int* __restrict__ cursor,
    const int* __restrict__ blockSums, int n, int total)
{
    const int idx = blockIdx.x * blockDim.x + threadIdx.x;
    if (idx < n) {
        const int v = offs[idx] + blockSums[idx / SCAN_TILE];
        offs[idx] = v;
        cursor[idx] = v;
    }
    if (idx == n) offs[n] = total;
}

__global__ __launch_bounds__(256) void reorder_k(
    const int* __restrict__ src, const int* __restrict__ dst,
    const float* __restrict__ ew, int* __restrict__ cursor,
    int* __restrict__ esrc, float* __restrict__ ewgt, int E)
{
    const int e = blockIdx.x * blockDim.x + threadIdx.x;
    if (e >= E) return;
    const int p = atomicAdd(&cursor[dst[e]], 1);
    esrc[p] = src[e];
    ewgt[p] = ew[e];
}

// ---------------- gather-side aggregation (bf16 payload) ----------------

// F=128: one wave per node, 2 bf16 (one dword) per lane; fused bias+relu.
// Writes fp32 row to `out` and a bf16 copy to `out_bf` (layer-2 GEMM input).
__global__ __launch_bounds__(256) void agg_f128b(
    const u16* __restrict__ sup, const int* __restrict__ offs,
    const int* __restrict__ esrc, const float* __restrict__ ewgt,
    const float* __restrict__ bias, float* __restrict__ out,
    u16* __restrict__ out_bf, int N)
{
    const int node = (blockIdx.x * blockDim.x + threadIdx.x) >> 6;
    const int lane = threadIdx.x & 63;
    if (node >= N) return;

    const int beg = offs[node];
    const int end = offs[node + 1];

    float a0x = 0.f, a0y = 0.f, a1x = 0.f, a1y = 0.f;
    int j = beg;
    for (; j + 1 < end; j += 2) {
        const int s0 = esrc[j];
        const int s1 = esrc[j + 1];
        const float w0 = ewgt[j];
        const float w1 = ewgt[j + 1];
        const unsigned v0 = *(const unsigned*)&sup[(size_t)s0 * 128 + lane * 2];
        const unsigned v1 = *(const unsigned*)&sup[(size_t)s1 * 128 + lane * 2];
        a0x = fmaf(bf2f(v0 & 0xffffu), w0, a0x);
        a0y = fmaf(bf2f(v0 >> 16),     w0, a0y);
        a1x = fmaf(bf2f(v1 & 0xffffu), w1, a1x);
        a1y = fmaf(bf2f(v1 >> 16),     w1, a1y);
    }
    if (j < end) {
        const float w0 = ewgt[j];
        const unsigned v0 = *(const unsigned*)&sup[(size_t)esrc[j] * 128 + lane * 2];
        a0x = fmaf(bf2f(v0 & 0xffffu), w0, a0x);
        a0y = fmaf(bf2f(v0 >> 16),     w0, a0y);
    }
    const float2 b = *(const float2*)&bias[lane * 2];
    const float ox = fmaxf(a0x + a1x + b.x, 0.f);
    const float oy = fmaxf(a0y + a1y + b.y, 0.f);
    *(float2*)&out[(size_t)node * 128 + lane * 2] = make_float2(ox, oy);
    const unsigned packed = (unsigned)f2bf(ox) | ((unsigned)f2bf(oy) << 16);
    *(unsigned*)&out_bf[(size_t)node * 128 + lane * 2] = packed;
}

// F=64: one wave per node, 1 bf16 per lane; fused bias + log_softmax.
__global__ __launch_bounds__(256) void agg_f64_lsm(
    const u16* __restrict__ sup, const int* __restrict__ offs,
    const int* __restrict__ esrc, const float* __restrict__ ewgt,
    const float* __restrict__ bias, float* __restrict__ out, int N)
{
    const int node = (blockIdx.x * blockDim.x + threadIdx.x) >> 6;
    const int lane = threadIdx.x & 63;
    if (node >= N) return;

    const int beg = offs[node];
    const int end = offs[node + 1];

    float a0 = 0.f, a1 = 0.f;
    int j = beg;
    for (; j + 1 < end; j += 2) {
        const int s0 = esrc[j];
        const int s1 = esrc[j + 1];
        a0 = fmaf(bf2f(sup[(size_t)s0 * 64 + lane]), ewgt[j],     a0);
        a1 = fmaf(bf2f(sup[(size_t)s1 * 64 + lane]), ewgt[j + 1], a1);
    }
    if (j < end)
        a0 = fmaf(bf2f(sup[(size_t)esrc[j] * 64 + lane]), ewgt[j], a0);

    const float z = a0 + a1 + bias[lane];
    float m = z;
#pragma unroll
    for (int o = 32; o > 0; o >>= 1) m = fmaxf(m, __shfl_xor(m, o, 64));
    const float ex = __expf(z - m);
    float s = ex;
#pragma unroll
    for (int o = 32; o > 0; o >>= 1) s += __shfl_xor(s, o, 64);
    out[(size_t)node * 64 + lane] = z - m - __logf(s);
}

// ---------------------------------------------------------------------------

extern "C" void kernel_launch(void* const* d_in, const int* in_sizes, int n_in,
                              void* d_out, int out_size, void* d_ws, size_t ws_size,
                              hipStream_t stream) {
    const float* feature = (const float*)d_in[0];
    const int*   src     = (const int*)d_in[1];
    const int*   dst     = (const int*)d_in[2];
    const float* ew      = (const float*)d_in[3];
    const float* W1      = (const float*)d_in[4];
    const float* b1      = (const float*)d_in[5];
    const float* W2      = (const float*)d_in[6];
    const float* b2      = (const float*)d_in[7];

    const int E    = in_sizes[1];
    const int H    = in_sizes[5];            // 128
    const int D    = in_sizes[7];            // 64
    const int F_IN = in_sizes[4] / H;        // 256
    const int N    = in_sizes[0] / F_IN;     // 100000

    float* out_x1 = (float*)d_out;                   // [N, H] fp32
    float* out_x2 = (float*)d_out + (size_t)N * H;   // [N, D] fp32

    // --- workspace carve-up (16B aligned) ---
    char* ws = (char*)d_ws;
    auto carve = [&](size_t bytes) {
        char* p = ws;
        ws += (bytes + 15) & ~(size_t)15;
        return p;
    };
    int*   counts    = (int*)  carve((size_t)N * sizeof(int));
    int*   offs      = (int*)  carve((size_t)(N + 1) * sizeof(int));
    int*   cursor    = (int*)  carve((size_t)N * sizeof(int));
    int*   blockSums = (int*)  carve(4096 * sizeof(int));
    int*   esrc      = (int*)  carve((size_t)E * sizeof(int));
    float* ewgt      = (float*)carve((size_t)E * sizeof(float));
    u16*   W1T       = (u16*)  carve((size_t)H * F_IN * sizeof(u16));
    u16*   W2T       = (u16*)  carve((size_t)D * H * sizeof(u16));
    u16*   supbf     = (u16*)  carve((size_t)N * H * sizeof(u16));  // sup1 / sup2 (aliased)
    u16*   x1bf      = (u16*)  carve((size_t)N * H * sizeof(u16));

    // --- CSR build ---
    hipMemsetAsync(counts, 0, (size_t)N * sizeof(int), stream);
    histogram_k<<<(E + 255) / 256, 256, 0, stream>>>(dst, counts, E);
    const int nScanBlocks = (N + SCAN_TILE - 1) / SCAN_TILE;
    scan_pass1<<<nScanBlocks, SCAN_B, 0, stream>>>(counts, offs, blockSums, N);
    scan_pass2<<<1, 64, 0, stream>>>(blockSums, nScanBlocks);
    scan_pass3<<<(N + 1 + SCAN_B - 1) / SCAN_B, SCAN_B, 0, stream>>>(offs, cursor, blockSums, N, E);
    reorder_k<<<(E + 255) / 256, 256, 0, stream>>>(src, dst, ew, cursor, esrc, ewgt, E);

    // --- weight prep ---
    transpose_cast<<<(F_IN * H + 255) / 256, 256, 0, stream>>>(W1, W1T, F_IN, H);
    transpose_cast<<<(H * D + 255) / 256, 256, 0, stream>>>(W2, W2T, H, D);

    // --- Layer 1 ---
    gemm_mfma<float, 128><<<dim3((N + 127) / 128), 256, 0, stream>>>(
        feature, W1T, supbf, N, F_IN);
    agg_f128b<<<(N * 64 + 255) / 256, 256, 0, stream>>>(
        supbf, offs, esrc, ewgt, b1, out_x1, x1bf, N);

    // --- Layer 2 ---
    gemm_mfma<u16, 64><<<dim3((N + 127) / 128), 256, 0, stream>>>(
        x1bf, W2T, supbf, N, H);
    agg_f64_lsm<<<(N * 64 + 255) / 256, 256, 0, stream>>>(
        supbf, offs, esrc, ewgt, b2, out_x2, N);
}

// Round 4
// 576.339 us; speedup vs baseline: 7.5044x; 1.0392x over previous
//
#include <hip/hip_runtime.h>
#include <hip/hip_bf16.h>
#include <type_traits>

// ---------------------------------------------------------------------------
// GCN forward, 2 layers. Round 4: uint2-packed edge reorder (one 8B store per
// edge), 4x-unrolled gather aggregation, vectorized histogram.
//
//  CSR build: histogram4 / scan x3 / reorder(uint2)
//  prep: W1^T, W2^T cast to bf16
//  gemm_mfma<float,128>: sup1bf = bf16(feature) @ W1
//  agg_f128b: x1 = relu(sum w*sup1bf[src] + b1) -> fp32 out + bf16 copy
//  gemm_mfma<u16,64>:    sup2bf = x1bf @ W2
//  agg_f64_lsm: out2 = log_softmax(sum w*sup2bf[src] + b2)
// ---------------------------------------------------------------------------

typedef unsigned short u16;

__device__ __forceinline__ u16 f2bf(float x) {
    union { float f; unsigned u; } v; v.f = x;
    const unsigned r = v.u + 0x7FFFu + ((v.u >> 16) & 1u);   // RNE
    return (u16)(r >> 16);
}
__device__ __forceinline__ float bf2f(unsigned h) {
    union { unsigned u; float f; } v; v.u = h << 16;
    return v.f;
}
__device__ __forceinline__ float uaf(unsigned u) {
    union { unsigned u; float f; } v; v.u = u;
    return v.f;
}

using short8  = __attribute__((ext_vector_type(8))) short;
using float4v = __attribute__((ext_vector_type(4))) float;

// ---------------- MFMA GEMM: C[M,BNt](bf16) = A[M,K] @ BT[BNt,K]^T ----------
template <typename AT, int BNt>
__global__ __launch_bounds__(256) void gemm_mfma(
    const AT* __restrict__ A, const u16* __restrict__ BT,
    u16* __restrict__ C, int M, int K)
{
    constexpr int BMt = 128;
    constexpr int WAVES_N = BNt / 64;
    constexpr int WROWS = 4 / WAVES_N;
    constexpr int WMF = BMt / (16 * WROWS);   // m-frags per wave
    constexpr int WNF = 4;                    // n-frags per wave (64 cols)

    __shared__ __align__(16) u16 As[BMt * 32];   // [m][k]
    __shared__ __align__(16) u16 Bs[BNt * 32];   // [n][k]

    const int tid  = threadIdx.x;
    const int lane = tid & 63;
    const int w    = tid >> 6;
    const int m0   = blockIdx.x * BMt;

    const int wm = (w % WROWS) * (WMF * 16);
    const int wn = (w / WROWS) * 64;

    const int fm = lane & 15;
    const int kh = lane >> 4;

    float4v acc[WMF][WNF] = {};

    for (int k0 = 0; k0 < K; k0 += 32) {
        __syncthreads();
        if constexpr (std::is_same<AT, float>::value) {
#pragma unroll
            for (int i = 0; i < 4; ++i) {
                const int s   = i * 256 + tid;
                const int row = s >> 3;
                const int seg = s & 7;
                const int gr  = min(m0 + row, M - 1);
                const float4 v = *(const float4*)&A[(size_t)gr * K + k0 + seg * 4];
                ushort4 o;
                o.x = f2bf(v.x); o.y = f2bf(v.y); o.z = f2bf(v.z); o.w = f2bf(v.w);
                *(ushort4*)&As[row * 32 + seg * 4] = o;
            }
        } else {
#pragma unroll
            for (int i = 0; i < 2; ++i) {
                const int s   = i * 256 + tid;
                const int row = s >> 2;
                const int seg = s & 3;
                const int gr  = min(m0 + row, M - 1);
                *(uint4*)&As[row * 32 + seg * 8] =
                    *(const uint4*)&A[(size_t)gr * K + k0 + seg * 8];
            }
        }
#pragma unroll
        for (int i = 0; i < BNt * 4 / 256; ++i) {
            const int s   = i * 256 + tid;
            const int row = s >> 2;
            const int seg = s & 3;
            *(uint4*)&Bs[row * 32 + seg * 8] =
                *(const uint4*)&BT[(size_t)row * K + k0 + seg * 8];
        }
        __syncthreads();

        short8 af[WMF], bfr[WNF];
#pragma unroll
        for (int i = 0; i < WMF; ++i)
            af[i] = *(const short8*)&As[(wm + i * 16 + fm) * 32 + kh * 8];
#pragma unroll
        for (int j = 0; j < WNF; ++j)
            bfr[j] = *(const short8*)&Bs[(wn + j * 16 + fm) * 32 + kh * 8];
#pragma unroll
        for (int i = 0; i < WMF; ++i)
#pragma unroll
            for (int j = 0; j < WNF; ++j)
                acc[i][j] = __builtin_amdgcn_mfma_f32_16x16x32_bf16(
                    af[i], bfr[j], acc[i][j], 0, 0, 0);
    }

#pragma unroll
    for (int i = 0; i < WMF; ++i) {
#pragma unroll
        for (int j = 0; j < WNF; ++j) {
            const int col = wn + j * 16 + fm;
#pragma unroll
            for (int r = 0; r < 4; ++r) {
                const int row = m0 + wm + i * 16 + kh * 4 + r;
                if (row < M) C[(size_t)row * BNt + col] = f2bf(acc[i][j][r]);
            }
        }
    }
}

// WT[n][k] = bf16(W[k][n])
__global__ __launch_bounds__(256) void transpose_cast(
    const float* __restrict__ W, u16* __restrict__ WT, int K, int Ncols)
{
    const int t = blockIdx.x * blockDim.x + threadIdx.x;
    if (t >= K * Ncols) return;
    const int k = t % K, n = t / K;
    WT[(size_t)n * K + k] = f2bf(W[(size_t)k * Ncols + n]);
}

// ---------------- CSR build ----------------

__global__ __launch_bounds__(256) void histogram4_k(
    const int* __restrict__ dst, int* __restrict__ counts, int E4, int E)
{
    const int t = blockIdx.x * blockDim.x + threadIdx.x;
    if (t < E4) {
        const int4 d = *(const int4*)&dst[t * 4];
        atomicAdd(&counts[d.x], 1);
        atomicAdd(&counts[d.y], 1);
        atomicAdd(&counts[d.z], 1);
        atomicAdd(&counts[d.w], 1);
    } else if (t == E4) {
        for (int e = E4 * 4; e < E; ++e) atomicAdd(&counts[dst[e]], 1);
    }
}

#define SCAN_B 256
#define SCAN_I 8
#define SCAN_TILE (SCAN_B * SCAN_I)   // 2048

__global__ __launch_bounds__(SCAN_B) void scan_pass1(
    const int* __restrict__ in, int* __restrict__ out,
    int* __restrict__ blockSums, int n)
{
    __shared__ int waveSums[SCAN_B / 64];
    const int tid = threadIdx.x;
    const int lane = tid & 63;
    const int wid = tid >> 6;
    const int base = blockIdx.x * SCAN_TILE + tid * SCAN_I;

    int items[SCAN_I];
    int tsum = 0;
#pragma unroll
    for (int i = 0; i < SCAN_I; ++i) {
        const int idx = base + i;
        items[i] = (idx < n) ? in[idx] : 0;
        tsum += items[i];
    }
    int x = tsum;
#pragma unroll
    for (int o = 1; o < 64; o <<= 1) {
        const int y = __shfl_up(x, o, 64);
        if (lane >= o) x += y;
    }
    if (lane == 63) waveSums[wid] = x;
    __syncthreads();
    if (tid == 0) {
        int acc = 0;
#pragma unroll
        for (int w = 0; w < SCAN_B / 64; ++w) {
            const int t = waveSums[w]; waveSums[w] = acc; acc += t;
        }
        blockSums[blockIdx.x] = acc;
    }
    __syncthreads();
    int texcl = x - tsum + waveSums[wid];
#pragma unroll
    for (int i = 0; i < SCAN_I; ++i) {
        const int idx = base + i;
        if (idx < n) out[idx] = texcl;
        texcl += items[i];
    }
}

__global__ void scan_pass2(int* __restrict__ blockSums, int nb)
{
    const int lane = threadIdx.x;
    int run = 0;
    for (int base = 0; base < nb; base += 64) {
        const int idx = base + lane;
        const int v = (idx < nb) ? blockSums[idx] : 0;
        int x = v;
#pragma unroll
        for (int o = 1; o < 64; o <<= 1) {
            const int y = __shfl_up(x, o, 64);
            if (lane >= o) x += y;
        }
        if (idx < nb) blockSums[idx] = run + x - v;
        run += __shfl(x, 63, 64);
    }
}

__global__ __launch_bounds__(SCAN_B) void scan_pass3(
    int* __restrict__ offs, int* __restrict__ cursor,
    const int* __restrict__ blockSums, int n, int total)
{
    const int idx = blockIdx.x * blockDim.x + threadIdx.x;
    if (idx < n) {
        const int v = offs[idx] + blockSums[idx / SCAN_TILE];
        offs[idx] = v;
        cursor[idx] = v;
    }
    if (idx == n) offs[n] = total;
}

// One 8B store per edge: epack[p] = {src, weight-bits}
__global__ __launch_bounds__(256) void reorder_k(
    const int* __restrict__ src, const int* __restrict__ dst,
    const float* __restrict__ ew, int* __restrict__ cursor,
    uint2* __restrict__ epack, int E)
{
    const int e = blockIdx.x * blockDim.x + threadIdx.x;
    if (e >= E) return;
    const int p = atomicAdd(&cursor[dst[e]], 1);
    uint2 v;
    v.x = (unsigned)src[e];
    union { float f; unsigned u; } wv; wv.f = ew[e];
    v.y = wv.u;
    epack[p] = v;
}

// ---------------- gather-side aggregation (bf16 payload) ----------------

// F=128: one wave per node, 2 bf16 (dword) per lane; 4 edges in flight.
__global__ __launch_bounds__(256) void agg_f128b(
    const u16* __restrict__ sup, const int* __restrict__ offs,
    const uint2* __restrict__ epack, const float* __restrict__ bias,
    float* __restrict__ out, u16* __restrict__ out_bf, int N)
{
    const int node = (blockIdx.x * blockDim.x + threadIdx.x) >> 6;
    const int lane = threadIdx.x & 63;
    if (node >= N) return;

    const int beg = offs[node];
    const int end = offs[node + 1];

    float ax[4] = {0.f, 0.f, 0.f, 0.f};
    float ay[4] = {0.f, 0.f, 0.f, 0.f};
    int j = beg;
    for (; j + 3 < end; j += 4) {
        const uint2 e0 = epack[j + 0];
        const uint2 e1 = epack[j + 1];
        const uint2 e2 = epack[j + 2];
        const uint2 e3 = epack[j + 3];
        const unsigned v0 = *(const unsigned*)&sup[(size_t)e0.x * 128 + lane * 2];
        const unsigned v1 = *(const unsigned*)&sup[(size_t)e1.x * 128 + lane * 2];
        const unsigned v2 = *(const unsigned*)&sup[(size_t)e2.x * 128 + lane * 2];
        const unsigned v3 = *(const unsigned*)&sup[(size_t)e3.x * 128 + lane * 2];
        ax[0] = fmaf(bf2f(v0 & 0xffffu), uaf(e0.y), ax[0]);
        ay[0] = fmaf(bf2f(v0 >> 16),     uaf(e0.y), ay[0]);
        ax[1] = fmaf(bf2f(v1 & 0xffffu), uaf(e1.y), ax[1]);
        ay[1] = fmaf(bf2f(v1 >> 16),     uaf(e1.y), ay[1]);
        ax[2] = fmaf(bf2f(v2 & 0xffffu), uaf(e2.y), ax[2]);
        ay[2] = fmaf(bf2f(v2 >> 16),     uaf(e2.y), ay[2]);
        ax[3] = fmaf(bf2f(v3 & 0xffffu), uaf(e3.y), ax[3]);
        ay[3] = fmaf(bf2f(v3 >> 16),     uaf(e3.y), ay[3]);
    }
    for (; j < end; ++j) {
        const uint2 e0 = epack[j];
        const unsigned v0 = *(const unsigned*)&sup[(size_t)e0.x * 128 + lane * 2];
        ax[0] = fmaf(bf2f(v0 & 0xffffu), uaf(e0.y), ax[0]);
        ay[0] = fmaf(bf2f(v0 >> 16),     uaf(e0.y), ay[0]);
    }
    const float2 b = *(const float2*)&bias[lane * 2];
    const float ox = fmaxf((ax[0] + ax[1]) + (ax[2] + ax[3]) + b.x, 0.f);
    const float oy = fmaxf((ay[0] + ay[1]) + (ay[2] + ay[3]) + b.y, 0.f);
    *(float2*)&out[(size_t)node * 128 + lane * 2] = make_float2(ox, oy);
    const unsigned packed = (unsigned)f2bf(ox) | ((unsigned)f2bf(oy) << 16);
    *(unsigned*)&out_bf[(size_t)node * 128 + lane * 2] = packed;
}

// F=64: one wave per node, 1 bf16 per lane; 4 edges in flight; fused log_softmax.
__global__ __launch_bounds__(256) void agg_f64_lsm(
    const u16* __restrict__ sup, const int* __restrict__ offs,
    const uint2* __restrict__ epack, const float* __restrict__ bias,
    float* __restrict__ out, int N)
{
    const int node = (blockIdx.x * blockDim.x + threadIdx.x) >> 6;
    const int lane = threadIdx.x & 63;
    if (node >= N) return;

    const int beg = offs[node];
    const int end = offs[node + 1];

    float a[4] = {0.f, 0.f, 0.f, 0.f};
    int j = beg;
    for (; j + 3 < end; j += 4) {
        const uint2 e0 = epack[j + 0];
        const uint2 e1 = epack[j + 1];
        const uint2 e2 = epack[j + 2];
        const uint2 e3 = epack[j + 3];
        const u16 v0 = sup[(size_t)e0.x * 64 + lane];
        const u16 v1 = sup[(size_t)e1.x * 64 + lane];
        const u16 v2 = sup[(size_t)e2.x * 64 + lane];
        const u16 v3 = sup[(size_t)e3.x * 64 + lane];
        a[0] = fmaf(bf2f(v0), uaf(e0.y), a[0]);
        a[1] = fmaf(bf2f(v1), uaf(e1.y), a[1]);
        a[2] = fmaf(bf2f(v2), uaf(e2.y), a[2]);
        a[3] = fmaf(bf2f(v3), uaf(e3.y), a[3]);
    }
    for (; j < end; ++j) {
        const uint2 e0 = epack[j];
        a[0] = fmaf(bf2f(sup[(size_t)e0.x * 64 + lane]), uaf(e0.y), a[0]);
    }

    const float z = (a[0] + a[1]) + (a[2] + a[3]) + bias[lane];
    float m = z;
#pragma unroll
    for (int o = 32; o > 0; o >>= 1) m = fmaxf(m, __shfl_xor(m, o, 64));
    const float ex = __expf(z - m);
    float s = ex;
#pragma unroll
    for (int o = 32; o > 0; o >>= 1) s += __shfl_xor(s, o, 64);
    out[(size_t)node * 64 + lane] = z - m - __logf(s);
}

// ---------------------------------------------------------------------------

extern "C" void kernel_launch(void* const* d_in, const int* in_sizes, int n_in,
                              void* d_out, int out_size, void* d_ws, size_t ws_size,
                              hipStream_t stream) {
    const float* feature = (const float*)d_in[0];
    const int*   src     = (const int*)d_in[1];
    const int*   dst     = (const int*)d_in[2];
    const float* ew      = (const float*)d_in[3];
    const float* W1      = (const float*)d_in[4];
    const float* b1      = (const float*)d_in[5];
    const float* W2      = (const float*)d_in[6];
    const float* b2      = (const float*)d_in[7];

    const int E    = in_sizes[1];
    const int H    = in_sizes[5];            // 128
    const int D    = in_sizes[7];            // 64
    const int F_IN = in_sizes[4] / H;        // 256
    const int N    = in_sizes[0] / F_IN;     // 100000

    float* out_x1 = (float*)d_out;                   // [N, H] fp32
    float* out_x2 = (float*)d_out + (size_t)N * H;   // [N, D] fp32

    char* ws = (char*)d_ws;
    auto carve = [&](size_t bytes) {
        char* p = ws;
        ws += (bytes + 15) & ~(size_t)15;
        return p;
    };
    int*   counts    = (int*)  carve((size_t)N * sizeof(int));
    int*   offs      = (int*)  carve((size_t)(N + 1) * sizeof(int));
    int*   cursor    = (int*)  carve((size_t)N * sizeof(int));
    int*   blockSums = (int*)  carve(4096 * sizeof(int));
    uint2* epack     = (uint2*)carve((size_t)E * sizeof(uint2));
    u16*   W1T       = (u16*)  carve((size_t)H * F_IN * sizeof(u16));
    u16*   W2T       = (u16*)  carve((size_t)D * H * sizeof(u16));
    u16*   supbf     = (u16*)  carve((size_t)N * H * sizeof(u16));
    u16*   x1bf      = (u16*)  carve((size_t)N * H * sizeof(u16));

    // --- CSR build ---
    hipMemsetAsync(counts, 0, (size_t)N * sizeof(int), stream);
    const int E4 = E / 4;
    histogram4_k<<<(E4 + 256) / 256, 256, 0, stream>>>(dst, counts, E4, E);
    const int nScanBlocks = (N + SCAN_TILE - 1) / SCAN_TILE;
    scan_pass1<<<nScanBlocks, SCAN_B, 0, stream>>>(counts, offs, blockSums, N);
    scan_pass2<<<1, 64, 0, stream>>>(blockSums, nScanBlocks);
    scan_pass3<<<(N + 1 + SCAN_B - 1) / SCAN_B, SCAN_B, 0, stream>>>(offs, cursor, blockSums, N, E);
    reorder_k<<<(E + 255) / 256, 256, 0, stream>>>(src, dst, ew, cursor, epack, E);

    // --- weight prep ---
    transpose_cast<<<(F_IN * H + 255) / 256, 256, 0, stream>>>(W1, W1T, F_IN, H);
    transpose_cast<<<(H * D + 255) / 256, 256, 0, stream>>>(W2, W2T, H, D);

    // --- Layer 1 ---
    gemm_mfma<float, 128><<<dim3((N + 127) / 128), 256, 0, stream>>>(
        feature, W1T, supbf, N, F_IN);
    agg_f128b<<<(N * 64 + 255) / 256, 256, 0, stream>>>(
        supbf, offs, epack, b1, out_x1, x1bf, N);

    // --- Layer 2 ---
    gemm_mfma<u16, 64><<<dim3((N + 127) / 128), 256, 0, stream>>>(
        x1bf, W2T, supbf, N, H);
    agg_f64_lsm<<<(N * 64 + 255) / 256, 256, 0, stream>>>(
        supbf, offs, epack, b2, out_x2, N);
}

// Round 5
// 561.466 us; speedup vs baseline: 7.7032x; 1.0265x over previous
//
#include <hip/hip_runtime.h>
#include <hip/hip_bf16.h>
#include <type_traits>

// ---------------------------------------------------------------------------
// GCN forward, 2 layers. Round 5: reorder with 8 edges/thread (MLP for the
// atomic->scatter latency chain), 8-deep unroll in gather aggregation.
//
//  CSR build: histogram4 / scan x3 / reorder8(uint2)
//  prep: W1^T, W2^T cast to bf16
//  gemm_mfma<float,128>: sup1bf = bf16(feature) @ W1
//  agg_f128b: x1 = relu(sum w*sup1bf[src] + b1) -> fp32 out + bf16 copy
//  gemm_mfma<u16,64>:    sup2bf = x1bf @ W2
//  agg_f64_lsm: out2 = log_softmax(sum w*sup2bf[src] + b2)
// ---------------------------------------------------------------------------

typedef unsigned short u16;

__device__ __forceinline__ u16 f2bf(float x) {
    union { float f; unsigned u; } v; v.f = x;
    const unsigned r = v.u + 0x7FFFu + ((v.u >> 16) & 1u);   // RNE
    return (u16)(r >> 16);
}
__device__ __forceinline__ float bf2f(unsigned h) {
    union { unsigned u; float f; } v; v.u = h << 16;
    return v.f;
}
__device__ __forceinline__ float uaf(unsigned u) {
    union { unsigned u; float f; } v; v.u = u;
    return v.f;
}
__device__ __forceinline__ unsigned fau(float f) {
    union { float f; unsigned u; } v; v.f = f;
    return v.u;
}

using short8  = __attribute__((ext_vector_type(8))) short;
using float4v = __attribute__((ext_vector_type(4))) float;

// ---------------- MFMA GEMM: C[M,BNt](bf16) = A[M,K] @ BT[BNt,K]^T ----------
template <typename AT, int BNt>
__global__ __launch_bounds__(256) void gemm_mfma(
    const AT* __restrict__ A, const u16* __restrict__ BT,
    u16* __restrict__ C, int M, int K)
{
    constexpr int BMt = 128;
    constexpr int WAVES_N = BNt / 64;
    constexpr int WROWS = 4 / WAVES_N;
    constexpr int WMF = BMt / (16 * WROWS);   // m-frags per wave
    constexpr int WNF = 4;                    // n-frags per wave (64 cols)

    __shared__ __align__(16) u16 As[BMt * 32];   // [m][k]
    __shared__ __align__(16) u16 Bs[BNt * 32];   // [n][k]

    const int tid  = threadIdx.x;
    const int lane = tid & 63;
    const int w    = tid >> 6;
    const int m0   = blockIdx.x * BMt;

    const int wm = (w % WROWS) * (WMF * 16);
    const int wn = (w / WROWS) * 64;

    const int fm = lane & 15;
    const int kh = lane >> 4;

    float4v acc[WMF][WNF] = {};

    for (int k0 = 0; k0 < K; k0 += 32) {
        __syncthreads();
        if constexpr (std::is_same<AT, float>::value) {
#pragma unroll
            for (int i = 0; i < 4; ++i) {
                const int s   = i * 256 + tid;
                const int row = s >> 3;
                const int seg = s & 7;
                const int gr  = min(m0 + row, M - 1);
                const float4 v = *(const float4*)&A[(size_t)gr * K + k0 + seg * 4];
                ushort4 o;
                o.x = f2bf(v.x); o.y = f2bf(v.y); o.z = f2bf(v.z); o.w = f2bf(v.w);
                *(ushort4*)&As[row * 32 + seg * 4] = o;
            }
        } else {
#pragma unroll
            for (int i = 0; i < 2; ++i) {
                const int s   = i * 256 + tid;
                const int row = s >> 2;
                const int seg = s & 3;
                const int gr  = min(m0 + row, M - 1);
                *(uint4*)&As[row * 32 + seg * 8] =
                    *(const uint4*)&A[(size_t)gr * K + k0 + seg * 8];
            }
        }
#pragma unroll
        for (int i = 0; i < BNt * 4 / 256; ++i) {
            const int s   = i * 256 + tid;
            const int row = s >> 2;
            const int seg = s & 3;
            *(uint4*)&Bs[row * 32 + seg * 8] =
                *(const uint4*)&BT[(size_t)row * K + k0 + seg * 8];
        }
        __syncthreads();

        short8 af[WMF], bfr[WNF];
#pragma unroll
        for (int i = 0; i < WMF; ++i)
            af[i] = *(const short8*)&As[(wm + i * 16 + fm) * 32 + kh * 8];
#pragma unroll
        for (int j = 0; j < WNF; ++j)
            bfr[j] = *(const short8*)&Bs[(wn + j * 16 + fm) * 32 + kh * 8];
#pragma unroll
        for (int i = 0; i < WMF; ++i)
#pragma unroll
            for (int j = 0; j < WNF; ++j)
                acc[i][j] = __builtin_amdgcn_mfma_f32_16x16x32_bf16(
                    af[i], bfr[j], acc[i][j], 0, 0, 0);
    }

#pragma unroll
    for (int i = 0; i < WMF; ++i) {
#pragma unroll
        for (int j = 0; j < WNF; ++j) {
            const int col = wn + j * 16 + fm;
#pragma unroll
            for (int r = 0; r < 4; ++r) {
                const int row = m0 + wm + i * 16 + kh * 4 + r;
                if (row < M) C[(size_t)row * BNt + col] = f2bf(acc[i][j][r]);
            }
        }
    }
}

// WT[n][k] = bf16(W[k][n])
__global__ __launch_bounds__(256) void transpose_cast(
    const float* __restrict__ W, u16* __restrict__ WT, int K, int Ncols)
{
    const int t = blockIdx.x * blockDim.x + threadIdx.x;
    if (t >= K * Ncols) return;
    const int k = t % K, n = t / K;
    WT[(size_t)n * K + k] = f2bf(W[(size_t)k * Ncols + n]);
}

// ---------------- CSR build ----------------

__global__ __launch_bounds__(256) void histogram4_k(
    const int* __restrict__ dst, int* __restrict__ counts, int E4, int E)
{
    const int t = blockIdx.x * blockDim.x + threadIdx.x;
    if (t < E4) {
        const int4 d = *(const int4*)&dst[t * 4];
        atomicAdd(&counts[d.x], 1);
        atomicAdd(&counts[d.y], 1);
        atomicAdd(&counts[d.z], 1);
        atomicAdd(&counts[d.w], 1);
    } else if (t == E4) {
        for (int e = E4 * 4; e < E; ++e) atomicAdd(&counts[dst[e]], 1);
    }
}

#define SCAN_B 256
#define SCAN_I 8
#define SCAN_TILE (SCAN_B * SCAN_I)   // 2048

__global__ __launch_bounds__(SCAN_B) void scan_pass1(
    const int* __restrict__ in, int* __restrict__ out,
    int* __restrict__ blockSums, int n)
{
    __shared__ int waveSums[SCAN_B / 64];
    const int tid = threadIdx.x;
    const int lane = tid & 63;
    const int wid = tid >> 6;
    const int base = blockIdx.x * SCAN_TILE + tid * SCAN_I;

    int items[SCAN_I];
    int tsum = 0;
#pragma unroll
    for (int i = 0; i < SCAN_I; ++i) {
        const int idx = base + i;
        items[i] = (idx < n) ? in[idx] : 0;
        tsum += items[i];
    }
    int x = tsum;
#pragma unroll
    for (int o = 1; o < 64; o <<= 1) {
        const int y = __shfl_up(x, o, 64);
        if (lane >= o) x += y;
    }
    if (lane == 63) waveSums[wid] = x;
    __syncthreads();
    if (tid == 0) {
        int acc = 0;
#pragma unroll
        for (int w = 0; w < SCAN_B / 64; ++w) {
            const int t = waveSums[w]; waveSums[w] = acc; acc += t;
        }
        blockSums[blockIdx.x] = acc;
    }
    __syncthreads();
    int texcl = x - tsum + waveSums[wid];
#pragma unroll
    for (int i = 0; i < SCAN_I; ++i) {
        const int idx = base + i;
        if (idx < n) out[idx] = texcl;
        texcl += items[i];
    }
}

__global__ void scan_pass2(int* __restrict__ blockSums, int nb)
{
    const int lane = threadIdx.x;
    int run = 0;
    for (int base = 0; base < nb; base += 64) {
        const int idx = base + lane;
        const int v = (idx < nb) ? blockSums[idx] : 0;
        int x = v;
#pragma unroll
        for (int o = 1; o < 64; o <<= 1) {
            const int y = __shfl_up(x, o, 64);
            if (lane >= o) x += y;
        }
        if (idx < nb) blockSums[idx] = run + x - v;
        run += __shfl(x, 63, 64);
    }
}

__global__ __launch_bounds__(SCAN_B) void scan_pass3(
    int* __restrict__ offs, int* __restrict__ cursor,
    const int* __restrict__ blockSums, int n, int total)
{
    const int idx = blockIdx.x * blockDim.x + threadIdx.x;
    if (idx < n) {
        const int v = offs[idx] + blockSums[idx / SCAN_TILE];
        offs[idx] = v;
        cursor[idx] = v;
    }
    if (idx == n) offs[n] = total;
}

// 8 edges per thread: 8 independent atomic->store chains in flight.
#define EPT 8
__global__ __launch_bounds__(256) void reorder8_k(
    const int* __restrict__ src, const int* __restrict__ dst,
    const float* __restrict__ ew, int* __restrict__ cursor,
    uint2* __restrict__ epack, int E)
{
    const int base = (blockIdx.x * blockDim.x + threadIdx.x) * EPT;
    if (base >= E) return;

    if (base + EPT <= E) {
        const int4 d0 = *(const int4*)&dst[base];
        const int4 d1 = *(const int4*)&dst[base + 4];
        const int4 s0 = *(const int4*)&src[base];
        const int4 s1 = *(const int4*)&src[base + 4];
        const float4 w0 = *(const float4*)&ew[base];
        const float4 w1 = *(const float4*)&ew[base + 4];
        int p[EPT];
        p[0] = atomicAdd(&cursor[d0.x], 1);
        p[1] = atomicAdd(&cursor[d0.y], 1);
        p[2] = atomicAdd(&cursor[d0.z], 1);
        p[3] = atomicAdd(&cursor[d0.w], 1);
        p[4] = atomicAdd(&cursor[d1.x], 1);
        p[5] = atomicAdd(&cursor[d1.y], 1);
        p[6] = atomicAdd(&cursor[d1.z], 1);
        p[7] = atomicAdd(&cursor[d1.w], 1);
        epack[p[0]] = make_uint2((unsigned)s0.x, fau(w0.x));
        epack[p[1]] = make_uint2((unsigned)s0.y, fau(w0.y));
        epack[p[2]] = make_uint2((unsigned)s0.z, fau(w0.z));
        epack[p[3]] = make_uint2((unsigned)s0.w, fau(w0.w));
        epack[p[4]] = make_uint2((unsigned)s1.x, fau(w1.x));
        epack[p[5]] = make_uint2((unsigned)s1.y, fau(w1.y));
        epack[p[6]] = make_uint2((unsigned)s1.z, fau(w1.z));
        epack[p[7]] = make_uint2((unsigned)s1.w, fau(w1.w));
    } else {
        for (int e = base; e < E; ++e) {
            const int p = atomicAdd(&cursor[dst[e]], 1);
            epack[p] = make_uint2((unsigned)src[e], fau(ew[e]));
        }
    }
}

// ---------------- gather-side aggregation (bf16 payload) ----------------

// F=128: one wave per node, 2 bf16 (dword) per lane; 8 edges in flight.
__global__ __launch_bounds__(256) void agg_f128b(
    const u16* __restrict__ sup, const int* __restrict__ offs,
    const uint2* __restrict__ epack, const float* __restrict__ bias,
    float* __restrict__ out, u16* __restrict__ out_bf, int N)
{
    const int node = (blockIdx.x * blockDim.x + threadIdx.x) >> 6;
    const int lane = threadIdx.x & 63;
    if (node >= N) return;

    const int beg = offs[node];
    const int end = offs[node + 1];

    float ax[4] = {0.f, 0.f, 0.f, 0.f};
    float ay[4] = {0.f, 0.f, 0.f, 0.f};
    int j = beg;
    for (; j + 7 < end; j += 8) {
        uint2 e[8];
#pragma unroll
        for (int i = 0; i < 8; ++i) e[i] = epack[j + i];
        unsigned v[8];
#pragma unroll
        for (int i = 0; i < 8; ++i)
            v[i] = *(const unsigned*)&sup[(size_t)e[i].x * 128 + lane * 2];
#pragma unroll
        for (int i = 0; i < 8; ++i) {
            ax[i & 3] = fmaf(bf2f(v[i] & 0xffffu), uaf(e[i].y), ax[i & 3]);
            ay[i & 3] = fmaf(bf2f(v[i] >> 16),     uaf(e[i].y), ay[i & 3]);
        }
    }
    for (; j + 3 < end; j += 4) {
        uint2 e[4];
#pragma unroll
        for (int i = 0; i < 4; ++i) e[i] = epack[j + i];
        unsigned v[4];
#pragma unroll
        for (int i = 0; i < 4; ++i)
            v[i] = *(const unsigned*)&sup[(size_t)e[i].x * 128 + lane * 2];
#pragma unroll
        for (int i = 0; i < 4; ++i) {
            ax[i] = fmaf(bf2f(v[i] & 0xffffu), uaf(e[i].y), ax[i]);
            ay[i] = fmaf(bf2f(v[i] >> 16),     uaf(e[i].y), ay[i]);
        }
    }
    for (; j < end; ++j) {
        const uint2 e0 = epack[j];
        const unsigned v0 = *(const unsigned*)&sup[(size_t)e0.x * 128 + lane * 2];
        ax[0] = fmaf(bf2f(v0 & 0xffffu), uaf(e0.y), ax[0]);
        ay[0] = fmaf(bf2f(v0 >> 16),     uaf(e0.y), ay[0]);
    }
    const float2 b = *(const float2*)&bias[lane * 2];
    const float ox = fmaxf((ax[0] + ax[1]) + (ax[2] + ax[3]) + b.x, 0.f);
    const float oy = fmaxf((ay[0] + ay[1]) + (ay[2] + ay[3]) + b.y, 0.f);
    *(float2*)&out[(size_t)node * 128 + lane * 2] = make_float2(ox, oy);
    const unsigned packed = (unsigned)f2bf(ox) | ((unsigned)f2bf(oy) << 16);
    *(unsigned*)&out_bf[(size_t)node * 128 + lane * 2] = packed;
}

// F=64: one wave per node, 1 bf16 per lane; 8 edges in flight; fused log_softmax.
__global__ __launch_bounds__(256) void agg_f64_lsm(
    const u16* __restrict__ sup, const int* __restrict__ offs,
    const uint2* __restrict__ epack, const float* __restrict__ bias,
    float* __restrict__ out, int N)
{
    const int node = (blockIdx.x * blockDim.x + threadIdx.x) >> 6;
    const int lane = threadIdx.x & 63;
    if (node >= N) return;

    const int beg = offs[node];
    const int end = offs[node + 1];

    float a[4] = {0.f, 0.f, 0.f, 0.f};
    int j = beg;
    for (; j + 7 < end; j += 8) {
        uint2 e[8];
#pragma unroll
        for (int i = 0; i < 8; ++i) e[i] = epack[j + i];
        u16 v[8];
#pragma unroll
        for (int i = 0; i < 8; ++i) v[i] = sup[(size_t)e[i].x * 64 + lane];
#pragma unroll
        for (int i = 0; i < 8; ++i)
            a[i & 3] = fmaf(bf2f(v[i]), uaf(e[i].y), a[i & 3]);
    }
    for (; j + 3 < end; j += 4) {
        uint2 e[4];
#pragma unroll
        for (int i = 0; i < 4; ++i) e[i] = epack[j + i];
        u16 v[4];
#pragma unroll
        for (int i = 0; i < 4; ++i) v[i] = sup[(size_t)e[i].x * 64 + lane];
#pragma unroll
        for (int i = 0; i < 4; ++i)
            a[i] = fmaf(bf2f(v[i]), uaf(e[i].y), a[i]);
    }
    for (; j < end; ++j) {
        const uint2 e0 = epack[j];
        a[0] = fmaf(bf2f(sup[(size_t)e0.x * 64 + lane]), uaf(e0.y), a[0]);
    }

    const float z = (a[0] + a[1]) + (a[2] + a[3]) + bias[lane];
    float m = z;
#pragma unroll
    for (int o = 32; o > 0; o >>= 1) m = fmaxf(m, __shfl_xor(m, o, 64));
    const float ex = __expf(z - m);
    float s = ex;
#pragma unroll
    for (int o = 32; o > 0; o >>= 1) s += __shfl_xor(s, o, 64);
    out[(size_t)node * 64 + lane] = z - m - __logf(s);
}

// ---------------------------------------------------------------------------

extern "C" void kernel_launch(void* const* d_in, const int* in_sizes, int n_in,
                              void* d_out, int out_size, void* d_ws, size_t ws_size,
                              hipStream_t stream) {
    const float* feature = (const float*)d_in[0];
    const int*   src     = (const int*)d_in[1];
    const int*   dst     = (const int*)d_in[2];
    const float* ew      = (const float*)d_in[3];
    const float* W1      = (const float*)d_in[4];
    const float* b1      = (const float*)d_in[5];
    const float* W2      = (const float*)d_in[6];
    const float* b2      = (const float*)d_in[7];

    const int E    = in_sizes[1];
    const int H    = in_sizes[5];            // 128
    const int D    = in_sizes[7];            // 64
    const int F_IN = in_sizes[4] / H;        // 256
    const int N    = in_sizes[0] / F_IN;     // 100000

    float* out_x1 = (float*)d_out;                   // [N, H] fp32
    float* out_x2 = (float*)d_out + (size_t)N * H;   // [N, D] fp32

    char* ws = (char*)d_ws;
    auto carve = [&](size_t bytes) {
        char* p = ws;
        ws += (bytes + 15) & ~(size_t)15;
        return p;
    };
    int*   counts    = (int*)  carve((size_t)N * sizeof(int));
    int*   offs      = (int*)  carve((size_t)(N + 1) * sizeof(int));
    int*   cursor    = (int*)  carve((size_t)N * sizeof(int));
    int*   blockSums = (int*)  carve(4096 * sizeof(int));
    uint2* epack     = (uint2*)carve((size_t)E * sizeof(uint2));
    u16*   W1T       = (u16*)  carve((size_t)H * F_IN * sizeof(u16));
    u16*   W2T       = (u16*)  carve((size_t)D * H * sizeof(u16));
    u16*   supbf     = (u16*)  carve((size_t)N * H * sizeof(u16));
    u16*   x1bf      = (u16*)  carve((size_t)N * H * sizeof(u16));

    // --- CSR build ---
    hipMemsetAsync(counts, 0, (size_t)N * sizeof(int), stream);
    const int E4 = E / 4;
    histogram4_k<<<(E4 + 256) / 256, 256, 0, stream>>>(dst, counts, E4, E);
    const int nScanBlocks = (N + SCAN_TILE - 1) / SCAN_TILE;
    scan_pass1<<<nScanBlocks, SCAN_B, 0, stream>>>(counts, offs, blockSums, N);
    scan_pass2<<<1, 64, 0, stream>>>(blockSums, nScanBlocks);
    scan_pass3<<<(N + 1 + SCAN_B - 1) / SCAN_B, SCAN_B, 0, stream>>>(offs, cursor, blockSums, N, E);
    {
        const int nThreads = (E + EPT - 1) / EPT;
        reorder8_k<<<(nThreads + 255) / 256, 256, 0, stream>>>(src, dst, ew, cursor, epack, E);
    }

    // --- weight prep ---
    transpose_cast<<<(F_IN * H + 255) / 256, 256, 0, stream>>>(W1, W1T, F_IN, H);
    transpose_cast<<<(H * D + 255) / 256, 256, 0, stream>>>(W2, W2T, H, D);

    // --- Layer 1 ---
    gemm_mfma<float, 128><<<dim3((N + 127) / 128), 256, 0, stream>>>(
        feature, W1T, supbf, N, F_IN);
    agg_f128b<<<(N * 64 + 255) / 256, 256, 0, stream>>>(
        supbf, offs, epack, b1, out_x1, x1bf, N);

    // --- Layer 2 ---
    gemm_mfma<u16, 64><<<dim3((N + 127) / 128), 256, 0, stream>>>(
        x1bf, W2T, supbf, N, H);
    agg_f64_lsm<<<(N * 64 + 255) / 256, 256, 0, stream>>>(
        supbf, offs, epack, b2, out_x2, N);
}

// Round 6
// 539.246 us; speedup vs baseline: 8.0206x; 1.0412x over previous
//
#include <hip/hip_runtime.h>
#include <hip/hip_bf16.h>
#include <type_traits>

// ---------------------------------------------------------------------------
// GCN forward, 2 layers. Round 6:
//  - mega1: reorder (atomic-latency-bound) || gemm1 (MFMA-bound) in ONE
//    dispatch, block-partitioned -> reorder's idle execution slots host gemm1.
//  - W1T/W2T transpose folded into scan_pass3's dispatch.
//  - agg kernels: 2 nodes/wave (32 lanes each), 8-deep unroll -> 16
//    independent gather loads in flight per wave.
//
//  memset(counts); hist4; scan1; scan2; scan3+tc; mega1(reorder||gemm1);
//  agg_f128b; gemm2; agg_f64_lsm        (10 dispatches)
// ---------------------------------------------------------------------------

typedef unsigned short u16;

__device__ __forceinline__ u16 f2bf(float x) {
    union { float f; unsigned u; } v; v.f = x;
    const unsigned r = v.u + 0x7FFFu + ((v.u >> 16) & 1u);   // RNE
    return (u16)(r >> 16);
}
__device__ __forceinline__ float bf2f(unsigned h) {
    union { unsigned u; float f; } v; v.u = h << 16;
    return v.f;
}
__device__ __forceinline__ float uaf(unsigned u) {
    union { unsigned u; float f; } v; v.u = u;
    return v.f;
}
__device__ __forceinline__ unsigned fau(float f) {
    union { float f; unsigned u; } v; v.f = f;
    return v.u;
}

using short8  = __attribute__((ext_vector_type(8))) short;
using float4v = __attribute__((ext_vector_type(4))) float;

#define EPT 8

// ---------------- MFMA GEMM body: C[M,BNt](bf16) = A[M,K] @ BT[BNt,K]^T -----
template <typename AT, int BNt>
__device__ __forceinline__ void gemm_body(
    const int bix, const AT* __restrict__ A, const u16* __restrict__ BT,
    u16* __restrict__ C, const int M, const int K)
{
    constexpr int BMt = 128;
    constexpr int WAVES_N = BNt / 64;
    constexpr int WROWS = 4 / WAVES_N;
    constexpr int WMF = BMt / (16 * WROWS);   // m-frags per wave
    constexpr int WNF = 4;                    // n-frags per wave (64 cols)

    __shared__ __align__(16) u16 As[BMt * 32];   // [m][k]
    __shared__ __align__(16) u16 Bs[BNt * 32];   // [n][k]

    const int tid  = threadIdx.x;
    const int lane = tid & 63;
    const int w    = tid >> 6;
    const int m0   = bix * BMt;

    const int wm = (w % WROWS) * (WMF * 16);
    const int wn = (w / WROWS) * 64;

    const int fm = lane & 15;
    const int kh = lane >> 4;

    float4v acc[WMF][WNF] = {};

    for (int k0 = 0; k0 < K; k0 += 32) {
        __syncthreads();
        if constexpr (std::is_same<AT, float>::value) {
#pragma unroll
            for (int i = 0; i < 4; ++i) {
                const int s   = i * 256 + tid;
                const int row = s >> 3;
                const int seg = s & 7;
                const int gr  = min(m0 + row, M - 1);
                const float4 v = *(const float4*)&A[(size_t)gr * K + k0 + seg * 4];
                ushort4 o;
                o.x = f2bf(v.x); o.y = f2bf(v.y); o.z = f2bf(v.z); o.w = f2bf(v.w);
                *(ushort4*)&As[row * 32 + seg * 4] = o;
            }
        } else {
#pragma unroll
            for (int i = 0; i < 2; ++i) {
                const int s   = i * 256 + tid;
                const int row = s >> 2;
                const int seg = s & 3;
                const int gr  = min(m0 + row, M - 1);
                *(uint4*)&As[row * 32 + seg * 8] =
                    *(const uint4*)&A[(size_t)gr * K + k0 + seg * 8];
            }
        }
#pragma unroll
        for (int i = 0; i < BNt * 4 / 256; ++i) {
            const int s   = i * 256 + tid;
            const int row = s >> 2;
            const int seg = s & 3;
            *(uint4*)&Bs[row * 32 + seg * 8] =
                *(const uint4*)&BT[(size_t)row * K + k0 + seg * 8];
        }
        __syncthreads();

        short8 af[WMF], bfr[WNF];
#pragma unroll
        for (int i = 0; i < WMF; ++i)
            af[i] = *(const short8*)&As[(wm + i * 16 + fm) * 32 + kh * 8];
#pragma unroll
        for (int j = 0; j < WNF; ++j)
            bfr[j] = *(const short8*)&Bs[(wn + j * 16 + fm) * 32 + kh * 8];
#pragma unroll
        for (int i = 0; i < WMF; ++i)
#pragma unroll
            for (int j = 0; j < WNF; ++j)
                acc[i][j] = __builtin_amdgcn_mfma_f32_16x16x32_bf16(
                    af[i], bfr[j], acc[i][j], 0, 0, 0);
    }

#pragma unroll
    for (int i = 0; i < WMF; ++i) {
#pragma unroll
        for (int j = 0; j < WNF; ++j) {
            const int col = wn + j * 16 + fm;
#pragma unroll
            for (int r = 0; r < 4; ++r) {
                const int row = m0 + wm + i * 16 + kh * 4 + r;
                if (row < M) C[(size_t)row * BNt + col] = f2bf(acc[i][j][r]);
            }
        }
    }
}

__global__ __launch_bounds__(256) void gemm2_k(
    const u16* __restrict__ A, const u16* __restrict__ BT,
    u16* __restrict__ C, int M, int K)
{
    gemm_body<u16, 64>(blockIdx.x, A, BT, C, M, K);
}

// ---------------- mega1: reorder blocks || gemm1 blocks ---------------------
__global__ __launch_bounds__(256) void mega1_k(
    // reorder part (blocks [0, RB))
    const int* __restrict__ src, const int* __restrict__ dst,
    const float* __restrict__ ew, int* __restrict__ cursor,
    uint2* __restrict__ epack, int E, int RB,
    // gemm1 part (blocks [RB, RB+GB))
    const float* __restrict__ A, const u16* __restrict__ BT,
    u16* __restrict__ C, int M, int K)
{
    const int b = blockIdx.x;
    if (b < RB) {
        const int base = (b * 256 + threadIdx.x) * EPT;
        if (base >= E) return;
        if (base + EPT <= E) {
            const int4 d0 = *(const int4*)&dst[base];
            const int4 d1 = *(const int4*)&dst[base + 4];
            const int4 s0 = *(const int4*)&src[base];
            const int4 s1 = *(const int4*)&src[base + 4];
            const float4 w0 = *(const float4*)&ew[base];
            const float4 w1 = *(const float4*)&ew[base + 4];
            int p[EPT];
            p[0] = atomicAdd(&cursor[d0.x], 1);
            p[1] = atomicAdd(&cursor[d0.y], 1);
            p[2] = atomicAdd(&cursor[d0.z], 1);
            p[3] = atomicAdd(&cursor[d0.w], 1);
            p[4] = atomicAdd(&cursor[d1.x], 1);
            p[5] = atomicAdd(&cursor[d1.y], 1);
            p[6] = atomicAdd(&cursor[d1.z], 1);
            p[7] = atomicAdd(&cursor[d1.w], 1);
            epack[p[0]] = make_uint2((unsigned)s0.x, fau(w0.x));
            epack[p[1]] = make_uint2((unsigned)s0.y, fau(w0.y));
            epack[p[2]] = make_uint2((unsigned)s0.z, fau(w0.z));
            epack[p[3]] = make_uint2((unsigned)s0.w, fau(w0.w));
            epack[p[4]] = make_uint2((unsigned)s1.x, fau(w1.x));
            epack[p[5]] = make_uint2((unsigned)s1.y, fau(w1.y));
            epack[p[6]] = make_uint2((unsigned)s1.z, fau(w1.z));
            epack[p[7]] = make_uint2((unsigned)s1.w, fau(w1.w));
        } else {
            for (int e = base; e < E; ++e) {
                const int p = atomicAdd(&cursor[dst[e]], 1);
                epack[p] = make_uint2((unsigned)src[e], fau(ew[e]));
            }
        }
        return;
    }
    gemm_body<float, 128>(b - RB, A, BT, C, M, K);
}

// ---------------- CSR build ----------------

__global__ __launch_bounds__(256) void histogram4_k(
    const int* __restrict__ dst, int* __restrict__ counts, int E4, int E)
{
    const int t = blockIdx.x * blockDim.x + threadIdx.x;
    if (t < E4) {
        const int4 d = *(const int4*)&dst[t * 4];
        atomicAdd(&counts[d.x], 1);
        atomicAdd(&counts[d.y], 1);
        atomicAdd(&counts[d.z], 1);
        atomicAdd(&counts[d.w], 1);
    } else if (t == E4) {
        for (int e = E4 * 4; e < E; ++e) atomicAdd(&counts[dst[e]], 1);
    }
}

#define SCAN_B 256
#define SCAN_I 8
#define SCAN_TILE (SCAN_B * SCAN_I)   // 2048

__global__ __launch_bounds__(SCAN_B) void scan_pass1(
    const int* __restrict__ in, int* __restrict__ out,
    int* __restrict__ blockSums, int n)
{
    __shared__ int waveSums[SCAN_B / 64];
    const int tid = threadIdx.x;
    const int lane = tid & 63;
    const int wid = tid >> 6;
    const int base = blockIdx.x * SCAN_TILE + tid * SCAN_I;

    int items[SCAN_I];
    int tsum = 0;
#pragma unroll
    for (int i = 0; i < SCAN_I; ++i) {
        const int idx = base + i;
        items[i] = (idx < n) ? in[idx] : 0;
        tsum += items[i];
    }
    int x = tsum;
#pragma unroll
    for (int o = 1; o < 64; o <<= 1) {
        const int y = __shfl_up(x, o, 64);
        if (lane >= o) x += y;
    }
    if (lane == 63) waveSums[wid] = x;
    __syncthreads();
    if (tid == 0) {
        int acc = 0;
#pragma unroll
        for (int w = 0; w < SCAN_B / 64; ++w) {
            const int t = waveSums[w]; waveSums[w] = acc; acc += t;
        }
        blockSums[blockIdx.x] = acc;
    }
    __syncthreads();
    int texcl = x - tsum + waveSums[wid];
#pragma unroll
    for (int i = 0; i < SCAN_I; ++i) {
        const int idx = base + i;
        if (idx < n) out[idx] = texcl;
        texcl += items[i];
    }
}

__global__ void scan_pass2(int* __restrict__ blockSums, int nb)
{
    const int lane = threadIdx.x;
    int run = 0;
    for (int base = 0; base < nb; base += 64) {
        const int idx = base + lane;
        const int v = (idx < nb) ? blockSums[idx] : 0;
        int x = v;
#pragma unroll
        for (int o = 1; o < 64; o <<= 1) {
            const int y = __shfl_up(x, o, 64);
            if (lane >= o) x += y;
        }
        if (idx < nb) blockSums[idx] = run + x - v;
        run += __shfl(x, 63, 64);
    }
}

// scan_pass3 blocks [0,SB) + weight transpose/cast blocks [SB, ...)
__global__ __launch_bounds__(SCAN_B) void scan3_tc_k(
    int* __restrict__ offs, int* __restrict__ cursor,
    const int* __restrict__ blockSums, int n, int total, int SB,
    const float* __restrict__ W1, u16* __restrict__ W1T, int K1, int N1,
    const float* __restrict__ W2, u16* __restrict__ W2T, int K2, int N2)
{
    const int b = blockIdx.x;
    if (b < SB) {
        const int idx = b * SCAN_B + threadIdx.x;
        if (idx < n) {
            const int v = offs[idx] + blockSums[idx / SCAN_TILE];
            offs[idx] = v;
            cursor[idx] = v;
        }
        if (idx == n) offs[n] = total;
        return;
    }
    const int t = (b - SB) * SCAN_B + threadIdx.x;
    const int tot1 = K1 * N1;
    if (t < tot1) {
        const int k = t % K1, nn = t / K1;
        W1T[(size_t)nn * K1 + k] = f2bf(W1[(size_t)k * N1 + nn]);
    } else {
        const int t2 = t - tot1;
        if (t2 < K2 * N2) {
            const int k = t2 % K2, nn = t2 / K2;
            W2T[(size_t)nn * K2 + k] = f2bf(W2[(size_t)k * N2 + nn]);
        }
    }
}

// ---------------- gather-side aggregation (bf16 payload) ----------------
// 2 nodes per wave: lanes 0..31 = node A, lanes 32..63 = node B.

// F=128: 4 bf16 (uint2) per lane; 8 edges in flight per half-wave.
__global__ __launch_bounds__(256) void agg_f128b(
    const u16* __restrict__ sup, const int* __restrict__ offs,
    const uint2* __restrict__ epack, const float* __restrict__ bias,
    float* __restrict__ out, u16* __restrict__ out_bf, int N)
{
    const int node = (blockIdx.x * blockDim.x + threadIdx.x) >> 5;
    const int hl = threadIdx.x & 31;
    if (node >= N) return;

    const int beg = offs[node];
    const int end = offs[node + 1];

    float a[4][4] = {};
    int j = beg;
    for (; j + 7 < end; j += 8) {
        uint2 e[8];
#pragma unroll
        for (int i = 0; i < 8; ++i) e[i] = epack[j + i];
        uint2 v[8];
#pragma unroll
        for (int i = 0; i < 8; ++i)
            v[i] = *(const uint2*)&sup[(size_t)e[i].x * 128 + hl * 4];
#pragma unroll
        for (int i = 0; i < 8; ++i) {
            const float w = uaf(e[i].y);
            a[i & 3][0] = fmaf(bf2f(v[i].x & 0xffffu), w, a[i & 3][0]);
            a[i & 3][1] = fmaf(bf2f(v[i].x >> 16),     w, a[i & 3][1]);
            a[i & 3][2] = fmaf(bf2f(v[i].y & 0xffffu), w, a[i & 3][2]);
            a[i & 3][3] = fmaf(bf2f(v[i].y >> 16),     w, a[i & 3][3]);
        }
    }
    for (; j < end; ++j) {
        const uint2 e0 = epack[j];
        const float w = uaf(e0.y);
        const uint2 v0 = *(const uint2*)&sup[(size_t)e0.x * 128 + hl * 4];
        a[0][0] = fmaf(bf2f(v0.x & 0xffffu), w, a[0][0]);
        a[0][1] = fmaf(bf2f(v0.x >> 16),     w, a[0][1]);
        a[0][2] = fmaf(bf2f(v0.y & 0xffffu), w, a[0][2]);
        a[0][3] = fmaf(bf2f(v0.y >> 16),     w, a[0][3]);
    }
    const float4 b4 = *(const float4*)&bias[hl * 4];
    const float o0 = fmaxf((a[0][0] + a[1][0]) + (a[2][0] + a[3][0]) + b4.x, 0.f);
    const float o1 = fmaxf((a[0][1] + a[1][1]) + (a[2][1] + a[3][1]) + b4.y, 0.f);
    const float o2 = fmaxf((a[0][2] + a[1][2]) + (a[2][2] + a[3][2]) + b4.z, 0.f);
    const float o3 = fmaxf((a[0][3] + a[1][3]) + (a[2][3] + a[3][3]) + b4.w, 0.f);
    *(float4*)&out[(size_t)node * 128 + hl * 4] = make_float4(o0, o1, o2, o3);
    ushort4 pb;
    pb.x = f2bf(o0); pb.y = f2bf(o1); pb.z = f2bf(o2); pb.w = f2bf(o3);
    *(ushort4*)&out_bf[(size_t)node * 128 + hl * 4] = pb;
}

// F=64: 2 bf16 (dword) per lane; 8 edges in flight per half-wave;
// fused bias + log_softmax (reduction within the 32-lane half).
__global__ __launch_bounds__(256) void agg_f64_lsm(
    const u16* __restrict__ sup, const int* __restrict__ offs,
    const uint2* __restrict__ epack, const float* __restrict__ bias,
    float* __restrict__ out, int N)
{
    const int node = (blockIdx.x * blockDim.x + threadIdx.x) >> 5;
    const int hl = threadIdx.x & 31;
    if (node >= N) return;

    const int beg = offs[node];
    const int end = offs[node + 1];

    float a[4][2] = {};
    int j = beg;
    for (; j + 7 < end; j += 8) {
        uint2 e[8];
#pragma unroll
        for (int i = 0; i < 8; ++i) e[i] = epack[j + i];
        unsigned v[8];
#pragma unroll
        for (int i = 0; i < 8; ++i)
            v[i] = *(const unsigned*)&sup[(size_t)e[i].x * 64 + hl * 2];
#pragma unroll
        for (int i = 0; i < 8; ++i) {
            const float w = uaf(e[i].y);
            a[i & 3][0] = fmaf(bf2f(v[i] & 0xffffu), w, a[i & 3][0]);
            a[i & 3][1] = fmaf(bf2f(v[i] >> 16),     w, a[i & 3][1]);
        }
    }
    for (; j < end; ++j) {
        const uint2 e0 = epack[j];
        const float w = uaf(e0.y);
        const unsigned v0 = *(const unsigned*)&sup[(size_t)e0.x * 64 + hl * 2];
        a[0][0] = fmaf(bf2f(v0 & 0xffffu), w, a[0][0]);
        a[0][1] = fmaf(bf2f(v0 >> 16),     w, a[0][1]);
    }

    const float2 b2 = *(const float2*)&bias[hl * 2];
    const float z0 = (a[0][0] + a[1][0]) + (a[2][0] + a[3][0]) + b2.x;
    const float z1 = (a[0][1] + a[1][1]) + (a[2][1] + a[3][1]) + b2.y;

    float m = fmaxf(z0, z1);
#pragma unroll
    for (int o = 16; o > 0; o >>= 1) m = fmaxf(m, __shfl_xor(m, o, 64));
    float s = __expf(z0 - m) + __expf(z1 - m);
#pragma unroll
    for (int o = 16; o > 0; o >>= 1) s += __shfl_xor(s, o, 64);
    const float ls = __logf(s);
    *(float2*)&out[(size_t)node * 64 + hl * 2] =
        make_float2(z0 - m - ls, z1 - m - ls);
}

// ---------------------------------------------------------------------------

extern "C" void kernel_launch(void* const* d_in, const int* in_sizes, int n_in,
                              void* d_out, int out_size, void* d_ws, size_t ws_size,
                              hipStream_t stream) {
    const float* feature = (const float*)d_in[0];
    const int*   src     = (const int*)d_in[1];
    const int*   dst     = (const int*)d_in[2];
    const float* ew      = (const float*)d_in[3];
    const float* W1      = (const float*)d_in[4];
    const float* b1      = (const float*)d_in[5];
    const float* W2      = (const float*)d_in[6];
    const float* b2      = (const float*)d_in[7];

    const int E    = in_sizes[1];
    const int H    = in_sizes[5];            // 128
    const int D    = in_sizes[7];            // 64
    const int F_IN = in_sizes[4] / H;        // 256
    const int N    = in_sizes[0] / F_IN;     // 100000

    float* out_x1 = (float*)d_out;                   // [N, H] fp32
    float* out_x2 = (float*)d_out + (size_t)N * H;   // [N, D] fp32

    char* ws = (char*)d_ws;
    auto carve = [&](size_t bytes) {
        char* p = ws;
        ws += (bytes + 15) & ~(size_t)15;
        return p;
    };
    int*   counts    = (int*)  carve((size_t)N * sizeof(int));
    int*   offs      = (int*)  carve((size_t)(N + 1) * sizeof(int));
    int*   cursor    = (int*)  carve((size_t)N * sizeof(int));
    int*   blockSums = (int*)  carve(4096 * sizeof(int));
    uint2* epack     = (uint2*)carve((size_t)E * sizeof(uint2));
    u16*   W1T       = (u16*)  carve((size_t)H * F_IN * sizeof(u16));
    u16*   W2T       = (u16*)  carve((size_t)D * H * sizeof(u16));
    u16*   supbf     = (u16*)  carve((size_t)N * H * sizeof(u16));
    u16*   x1bf      = (u16*)  carve((size_t)N * H * sizeof(u16));

    // --- CSR build prefix ---
    hipMemsetAsync(counts, 0, (size_t)N * sizeof(int), stream);
    const int E4 = E / 4;
    histogram4_k<<<(E4 + 256) / 256, 256, 0, stream>>>(dst, counts, E4, E);
    const int nScanBlocks = (N + SCAN_TILE - 1) / SCAN_TILE;
    scan_pass1<<<nScanBlocks, SCAN_B, 0, stream>>>(counts, offs, blockSums, N);
    scan_pass2<<<1, 64, 0, stream>>>(blockSums, nScanBlocks);
    {
        const int SB = (N + 1 + SCAN_B - 1) / SCAN_B;
        const int TCB = (F_IN * H + H * D + SCAN_B - 1) / SCAN_B;
        scan3_tc_k<<<SB + TCB, SCAN_B, 0, stream>>>(
            offs, cursor, blockSums, N, E, SB,
            W1, W1T, F_IN, H, W2, W2T, H, D);
    }

    // --- mega1: reorder || gemm1 ---
    {
        const int RB = ((E + EPT - 1) / EPT + 255) / 256;
        const int GB = (N + 127) / 128;
        mega1_k<<<RB + GB, 256, 0, stream>>>(
            src, dst, ew, cursor, epack, E, RB,
            feature, W1T, supbf, N, F_IN);
    }

    // --- agg layer 1 (fused bias+relu, dual output) ---
    agg_f128b<<<(N * 32 + 255) / 256, 256, 0, stream>>>(
        supbf, offs, epack, b1, out_x1, x1bf, N);

    // --- layer 2 ---
    gemm2_k<<<(N + 127) / 128, 256, 0, stream>>>(x1bf, W2T, supbf, N, H);
    agg_f64_lsm<<<(N * 32 + 255) / 256, 256, 0, stream>>>(
        supbf, offs, epack, b2, out_x2, N);
}

// Round 7
// 491.813 us; speedup vs baseline: 8.7942x; 1.0964x over previous
//
#include <hip/hip_runtime.h>
#include <hip/hip_bf16.h>
#include <type_traits>

// ---------------------------------------------------------------------------
// GCN forward, 2 layers. Round 7:
//  - mega0: histogram || gemm1-first-half, role interleaved by block parity.
//  - mega1: reorder   || gemm1-second-half, role interleaved by block parity
//    (R6 concatenated ranges -> phases serialized; parity fixes co-residency).
//  - agg kernels: 4 nodes/wave (16 lanes/node, 16B/lane) -> 32 gather loads
//    in flight per wave.
//
//  tc; memset(counts); mega0; scan1; scan2; scan3; mega1; agg1; gemm2; agg2
// ---------------------------------------------------------------------------

typedef unsigned short u16;

__device__ __forceinline__ u16 f2bf(float x) {
    union { float f; unsigned u; } v; v.f = x;
    const unsigned r = v.u + 0x7FFFu + ((v.u >> 16) & 1u);   // RNE
    return (u16)(r >> 16);
}
__device__ __forceinline__ float bf2f(unsigned h) {
    union { unsigned u; float f; } v; v.u = h << 16;
    return v.f;
}
__device__ __forceinline__ float uaf(unsigned u) {
    union { unsigned u; float f; } v; v.u = u;
    return v.f;
}
__device__ __forceinline__ unsigned fau(float f) {
    union { float f; unsigned u; } v; v.f = f;
    return v.u;
}

using short8  = __attribute__((ext_vector_type(8))) short;
using float4v = __attribute__((ext_vector_type(4))) float;

#define EPT 8

// ---------------- MFMA GEMM body: C[M,BNt](bf16) = A[M,K] @ BT[BNt,K]^T -----
template <typename AT, int BNt>
__device__ __forceinline__ void gemm_body(
    const int bix, const AT* __restrict__ A, const u16* __restrict__ BT,
    u16* __restrict__ C, const int M, const int K)
{
    constexpr int BMt = 128;
    constexpr int WAVES_N = BNt / 64;
    constexpr int WROWS = 4 / WAVES_N;
    constexpr int WMF = BMt / (16 * WROWS);   // m-frags per wave
    constexpr int WNF = 4;                    // n-frags per wave (64 cols)

    __shared__ __align__(16) u16 As[BMt * 32];   // [m][k]
    __shared__ __align__(16) u16 Bs[BNt * 32];   // [n][k]

    const int tid  = threadIdx.x;
    const int lane = tid & 63;
    const int w    = tid >> 6;
    const int m0   = bix * BMt;

    const int wm = (w % WROWS) * (WMF * 16);
    const int wn = (w / WROWS) * 64;

    const int fm = lane & 15;
    const int kh = lane >> 4;

    float4v acc[WMF][WNF] = {};

    for (int k0 = 0; k0 < K; k0 += 32) {
        __syncthreads();
        if constexpr (std::is_same<AT, float>::value) {
#pragma unroll
            for (int i = 0; i < 4; ++i) {
                const int s   = i * 256 + tid;
                const int row = s >> 3;
                const int seg = s & 7;
                const int gr  = min(m0 + row, M - 1);
                const float4 v = *(const float4*)&A[(size_t)gr * K + k0 + seg * 4];
                ushort4 o;
                o.x = f2bf(v.x); o.y = f2bf(v.y); o.z = f2bf(v.z); o.w = f2bf(v.w);
                *(ushort4*)&As[row * 32 + seg * 4] = o;
            }
        } else {
#pragma unroll
            for (int i = 0; i < 2; ++i) {
                const int s   = i * 256 + tid;
                const int row = s >> 2;
                const int seg = s & 3;
                const int gr  = min(m0 + row, M - 1);
                *(uint4*)&As[row * 32 + seg * 8] =
                    *(const uint4*)&A[(size_t)gr * K + k0 + seg * 8];
            }
        }
#pragma unroll
        for (int i = 0; i < BNt * 4 / 256; ++i) {
            const int s   = i * 256 + tid;
            const int row = s >> 2;
            const int seg = s & 3;
            *(uint4*)&Bs[row * 32 + seg * 8] =
                *(const uint4*)&BT[(size_t)row * K + k0 + seg * 8];
        }
        __syncthreads();

        short8 af[WMF], bfr[WNF];
#pragma unroll
        for (int i = 0; i < WMF; ++i)
            af[i] = *(const short8*)&As[(wm + i * 16 + fm) * 32 + kh * 8];
#pragma unroll
        for (int j = 0; j < WNF; ++j)
            bfr[j] = *(const short8*)&Bs[(wn + j * 16 + fm) * 32 + kh * 8];
#pragma unroll
        for (int i = 0; i < WMF; ++i)
#pragma unroll
            for (int j = 0; j < WNF; ++j)
                acc[i][j] = __builtin_amdgcn_mfma_f32_16x16x32_bf16(
                    af[i], bfr[j], acc[i][j], 0, 0, 0);
    }

#pragma unroll
    for (int i = 0; i < WMF; ++i) {
#pragma unroll
        for (int j = 0; j < WNF; ++j) {
            const int col = wn + j * 16 + fm;
#pragma unroll
            for (int r = 0; r < 4; ++r) {
                const int row = m0 + wm + i * 16 + kh * 4 + r;
                if (row < M) C[(size_t)row * BNt + col] = f2bf(acc[i][j][r]);
            }
        }
    }
}

__global__ __launch_bounds__(256) void gemm2_k(
    const u16* __restrict__ A, const u16* __restrict__ BT,
    u16* __restrict__ C, int M, int K)
{
    gemm_body<u16, 64>(blockIdx.x, A, BT, C, M, K);
}

// ---------------- weight transpose+cast (both weights, one tiny kernel) ----
__global__ __launch_bounds__(256) void tc_k(
    const float* __restrict__ W1, u16* __restrict__ W1T, int K1, int N1,
    const float* __restrict__ W2, u16* __restrict__ W2T, int K2, int N2)
{
    const int t = blockIdx.x * blockDim.x + threadIdx.x;
    const int tot1 = K1 * N1;
    if (t < tot1) {
        const int k = t % K1, nn = t / K1;
        W1T[(size_t)nn * K1 + k] = f2bf(W1[(size_t)k * N1 + nn]);
    } else {
        const int t2 = t - tot1;
        if (t2 < K2 * N2) {
            const int k = t2 % K2, nn = t2 / K2;
            W2T[(size_t)nn * K2 + k] = f2bf(W2[(size_t)k * N2 + nn]);
        }
    }
}

// ---------------- mega0: histogram || gemm1-first-half (parity) -------------
__global__ __launch_bounds__(256) void mega0_k(
    const int* __restrict__ dst, int* __restrict__ counts, int E4, int E,
    const float* __restrict__ A, const u16* __restrict__ BT,
    u16* __restrict__ C, int M, int K, int GA)
{
    const int b = blockIdx.x;
    int gemm_id = -1, hist_id;
    if (b < 2 * GA) {
        if ((b & 1) == 0) gemm_id = b >> 1;
        else hist_id = b >> 1;
    } else {
        hist_id = b - GA;
    }
    if (gemm_id >= 0) {
        gemm_body<float, 128>(gemm_id, A, BT, C, M, K);
        return;
    }
    const int t = hist_id * 256 + threadIdx.x;
    if (t < E4) {
        const int4 d = *(const int4*)&dst[t * 4];
        atomicAdd(&counts[d.x], 1);
        atomicAdd(&counts[d.y], 1);
        atomicAdd(&counts[d.z], 1);
        atomicAdd(&counts[d.w], 1);
    } else if (t == E4) {
        for (int e = E4 * 4; e < E; ++e) atomicAdd(&counts[dst[e]], 1);
    }
}

// ---------------- mega1: reorder || gemm1-second-half (parity) --------------
__global__ __launch_bounds__(256) void mega1_k(
    const int* __restrict__ src, const int* __restrict__ dst,
    const float* __restrict__ ew, int* __restrict__ cursor,
    uint2* __restrict__ epack, int E,
    const float* __restrict__ A, const u16* __restrict__ BT,
    u16* __restrict__ C, int M, int K, int GA, int GB2)
{
    const int b = blockIdx.x;
    int gemm_id = -1, ro_id;
    if (b < 2 * GB2) {
        if ((b & 1) == 0) gemm_id = b >> 1;
        else ro_id = b >> 1;
    } else {
        ro_id = b - GB2;
    }
    if (gemm_id >= 0) {
        gemm_body<float, 128>(GA + gemm_id, A, BT, C, M, K);
        return;
    }
    const int base = (ro_id * 256 + threadIdx.x) * EPT;
    if (base >= E) return;
    if (base + EPT <= E) {
        const int4 d0 = *(const int4*)&dst[base];
        const int4 d1 = *(const int4*)&dst[base + 4];
        const int4 s0 = *(const int4*)&src[base];
        const int4 s1 = *(const int4*)&src[base + 4];
        const float4 w0 = *(const float4*)&ew[base];
        const float4 w1 = *(const float4*)&ew[base + 4];
        int p[EPT];
        p[0] = atomicAdd(&cursor[d0.x], 1);
        p[1] = atomicAdd(&cursor[d0.y], 1);
        p[2] = atomicAdd(&cursor[d0.z], 1);
        p[3] = atomicAdd(&cursor[d0.w], 1);
        p[4] = atomicAdd(&cursor[d1.x], 1);
        p[5] = atomicAdd(&cursor[d1.y], 1);
        p[6] = atomicAdd(&cursor[d1.z], 1);
        p[7] = atomicAdd(&cursor[d1.w], 1);
        epack[p[0]] = make_uint2((unsigned)s0.x, fau(w0.x));
        epack[p[1]] = make_uint2((unsigned)s0.y, fau(w0.y));
        epack[p[2]] = make_uint2((unsigned)s0.z, fau(w0.z));
        epack[p[3]] = make_uint2((unsigned)s0.w, fau(w0.w));
        epack[p[4]] = make_uint2((unsigned)s1.x, fau(w1.x));
        epack[p[5]] = make_uint2((unsigned)s1.y, fau(w1.y));
        epack[p[6]] = make_uint2((unsigned)s1.z, fau(w1.z));
        epack[p[7]] = make_uint2((unsigned)s1.w, fau(w1.w));
    } else {
        for (int e = base; e < E; ++e) {
            const int p = atomicAdd(&cursor[dst[e]], 1);
            epack[p] = make_uint2((unsigned)src[e], fau(ew[e]));
        }
    }
}

// ---------------- scans ----------------

#define SCAN_B 256
#define SCAN_I 8
#define SCAN_TILE (SCAN_B * SCAN_I)   // 2048

__global__ __launch_bounds__(SCAN_B) void scan_pass1(
    const int* __restrict__ in, int* __restrict__ out,
    int* __restrict__ blockSums, int n)
{
    __shared__ int waveSums[SCAN_B / 64];
    const int tid = threadIdx.x;
    const int lane = tid & 63;
    const int wid = tid >> 6;
    const int base = blockIdx.x * SCAN_TILE + tid * SCAN_I;

    int items[SCAN_I];
    int tsum = 0;
#pragma unroll
    for (int i = 0; i < SCAN_I; ++i) {
        const int idx = base + i;
        items[i] = (idx < n) ? in[idx] : 0;
        tsum += items[i];
    }
    int x = tsum;
#pragma unroll
    for (int o = 1; o < 64; o <<= 1) {
        const int y = __shfl_up(x, o, 64);
        if (lane >= o) x += y;
    }
    if (lane == 63) waveSums[wid] = x;
    __syncthreads();
    if (tid == 0) {
        int acc = 0;
#pragma unroll
        for (int w = 0; w < SCAN_B / 64; ++w) {
            const int t = waveSums[w]; waveSums[w] = acc; acc += t;
        }
        blockSums[blockIdx.x] = acc;
    }
    __syncthreads();
    int texcl = x - tsum + waveSums[wid];
#pragma unroll
    for (int i = 0; i < SCAN_I; ++i) {
        const int idx = base + i;
        if (idx < n) out[idx] = texcl;
        texcl += items[i];
    }
}

__global__ void scan_pass2(int* __restrict__ blockSums, int nb)
{
    const int lane = threadIdx.x;
    int run = 0;
    for (int base = 0; base < nb; base += 64) {
        const int idx = base + lane;
        const int v = (idx < nb) ? blockSums[idx] : 0;
        int x = v;
#pragma unroll
        for (int o = 1; o < 64; o <<= 1) {
            const int y = __shfl_up(x, o, 64);
            if (lane >= o) x += y;
        }
        if (idx < nb) blockSums[idx] = run + x - v;
        run += __shfl(x, 63, 64);
    }
}

__global__ __launch_bounds__(SCAN_B) void scan_pass3(
    int* __restrict__ offs, int* __restrict__ cursor,
    const int* __restrict__ blockSums, int n, int total)
{
    const int idx = blockIdx.x * blockDim.x + threadIdx.x;
    if (idx < n) {
        const int v = offs[idx] + blockSums[idx / SCAN_TILE];
        offs[idx] = v;
        cursor[idx] = v;
    }
    if (idx == n) offs[n] = total;
}

// ---------------- gather-side aggregation (bf16 payload) ----------------
// 4 nodes per wave: 16 lanes per node, 16B (8 bf16) per lane.

// F=128: fused bias+relu; fp32 out + bf16 copy.
__global__ __launch_bounds__(256) void agg_f128b(
    const u16* __restrict__ sup, const int* __restrict__ offs,
    const uint2* __restrict__ epack, const float* __restrict__ bias,
    float* __restrict__ out, u16* __restrict__ out_bf, int N)
{
    const int node = (blockIdx.x * blockDim.x + threadIdx.x) >> 4;
    const int hl = threadIdx.x & 15;
    if (node >= N) return;

    const int beg = offs[node];
    const int end = offs[node + 1];

    float a[2][8] = {};
    int j = beg;
    for (; j + 7 < end; j += 8) {
        uint2 e[8];
#pragma unroll
        for (int i = 0; i < 8; ++i) e[i] = epack[j + i];
        uint4 v[8];
#pragma unroll
        for (int i = 0; i < 8; ++i)
            v[i] = *(const uint4*)&sup[(size_t)e[i].x * 128 + hl * 8];
#pragma unroll
        for (int i = 0; i < 8; ++i) {
            const float w = uaf(e[i].y);
            float* acc = a[i & 1];
            acc[0] = fmaf(bf2f(v[i].x & 0xffffu), w, acc[0]);
            acc[1] = fmaf(bf2f(v[i].x >> 16),     w, acc[1]);
            acc[2] = fmaf(bf2f(v[i].y & 0xffffu), w, acc[2]);
            acc[3] = fmaf(bf2f(v[i].y >> 16),     w, acc[3]);
            acc[4] = fmaf(bf2f(v[i].z & 0xffffu), w, acc[4]);
            acc[5] = fmaf(bf2f(v[i].z >> 16),     w, acc[5]);
            acc[6] = fmaf(bf2f(v[i].w & 0xffffu), w, acc[6]);
            acc[7] = fmaf(bf2f(v[i].w >> 16),     w, acc[7]);
        }
    }
    for (; j < end; ++j) {
        const uint2 e0 = epack[j];
        const float w = uaf(e0.y);
        const uint4 v0 = *(const uint4*)&sup[(size_t)e0.x * 128 + hl * 8];
        a[0][0] = fmaf(bf2f(v0.x & 0xffffu), w, a[0][0]);
        a[0][1] = fmaf(bf2f(v0.x >> 16),     w, a[0][1]);
        a[0][2] = fmaf(bf2f(v0.y & 0xffffu), w, a[0][2]);
        a[0][3] = fmaf(bf2f(v0.y >> 16),     w, a[0][3]);
        a[0][4] = fmaf(bf2f(v0.z & 0xffffu), w, a[0][4]);
        a[0][5] = fmaf(bf2f(v0.z >> 16),     w, a[0][5]);
        a[0][6] = fmaf(bf2f(v0.w & 0xffffu), w, a[0][6]);
        a[0][7] = fmaf(bf2f(v0.w >> 16),     w, a[0][7]);
    }
    const float4 b0 = *(const float4*)&bias[hl * 8];
    const float4 b1 = *(const float4*)&bias[hl * 8 + 4];
    float o[8];
    o[0] = fmaxf(a[0][0] + a[1][0] + b0.x, 0.f);
    o[1] = fmaxf(a[0][1] + a[1][1] + b0.y, 0.f);
    o[2] = fmaxf(a[0][2] + a[1][2] + b0.z, 0.f);
    o[3] = fmaxf(a[0][3] + a[1][3] + b0.w, 0.f);
    o[4] = fmaxf(a[0][4] + a[1][4] + b1.x, 0.f);
    o[5] = fmaxf(a[0][5] + a[1][5] + b1.y, 0.f);
    o[6] = fmaxf(a[0][6] + a[1][6] + b1.z, 0.f);
    o[7] = fmaxf(a[0][7] + a[1][7] + b1.w, 0.f);
    float* orow = &out[(size_t)node * 128 + hl * 8];
    *(float4*)&orow[0] = make_float4(o[0], o[1], o[2], o[3]);
    *(float4*)&orow[4] = make_float4(o[4], o[5], o[6], o[7]);
    uint4 pb;
    pb.x = (unsigned)f2bf(o[0]) | ((unsigned)f2bf(o[1]) << 16);
    pb.y = (unsigned)f2bf(o[2]) | ((unsigned)f2bf(o[3]) << 16);
    pb.z = (unsigned)f2bf(o[4]) | ((unsigned)f2bf(o[5]) << 16);
    pb.w = (unsigned)f2bf(o[6]) | ((unsigned)f2bf(o[7]) << 16);
    *(uint4*)&out_bf[(size_t)node * 128 + hl * 8] = pb;
}

// F=64: 4 bf16 (uint2) per lane; fused bias + log_softmax (16-lane reduce).
__global__ __launch_bounds__(256) void agg_f64_lsm(
    const u16* __restrict__ sup, const int* __restrict__ offs,
    const uint2* __restrict__ epack, const float* __restrict__ bias,
    float* __restrict__ out, int N)
{
    const int node = (blockIdx.x * blockDim.x + threadIdx.x) >> 4;
    const int hl = threadIdx.x & 15;
    if (node >= N) return;

    const int beg = offs[node];
    const int end = offs[node + 1];

    float a[2][4] = {};
    int j = beg;
    for (; j + 7 < end; j += 8) {
        uint2 e[8];
#pragma unroll
        for (int i = 0; i < 8; ++i) e[i] = epack[j + i];
        uint2 v[8];
#pragma unroll
        for (int i = 0; i < 8; ++i)
            v[i] = *(const uint2*)&sup[(size_t)e[i].x * 64 + hl * 4];
#pragma unroll
        for (int i = 0; i < 8; ++i) {
            const float w = uaf(e[i].y);
            float* acc = a[i & 1];
            acc[0] = fmaf(bf2f(v[i].x & 0xffffu), w, acc[0]);
            acc[1] = fmaf(bf2f(v[i].x >> 16),     w, acc[1]);
            acc[2] = fmaf(bf2f(v[i].y & 0xffffu), w, acc[2]);
            acc[3] = fmaf(bf2f(v[i].y >> 16),     w, acc[3]);
        }
    }
    for (; j < end; ++j) {
        const uint2 e0 = epack[j];
        const float w = uaf(e0.y);
        const uint2 v0 = *(const uint2*)&sup[(size_t)e0.x * 64 + hl * 4];
        a[0][0] = fmaf(bf2f(v0.x & 0xffffu), w, a[0][0]);
        a[0][1] = fmaf(bf2f(v0.x >> 16),     w, a[0][1]);
        a[0][2] = fmaf(bf2f(v0.y & 0xffffu), w, a[0][2]);
        a[0][3] = fmaf(bf2f(v0.y >> 16),     w, a[0][3]);
    }

    const float4 b4 = *(const float4*)&bias[hl * 4];
    float z[4];
    z[0] = a[0][0] + a[1][0] + b4.x;
    z[1] = a[0][1] + a[1][1] + b4.y;
    z[2] = a[0][2] + a[1][2] + b4.z;
    z[3] = a[0][3] + a[1][3] + b4.w;

    float m = fmaxf(fmaxf(z[0], z[1]), fmaxf(z[2], z[3]));
#pragma unroll
    for (int o = 8; o > 0; o >>= 1) m = fmaxf(m, __shfl_xor(m, o, 64));
    float s = __expf(z[0] - m) + __expf(z[1] - m) + __expf(z[2] - m) + __expf(z[3] - m);
#pragma unroll
    for (int o = 8; o > 0; o >>= 1) s += __shfl_xor(s, o, 64);
    const float ls = __logf(s);
    *(float4*)&out[(size_t)node * 64 + hl * 4] =
        make_float4(z[0] - m - ls, z[1] - m - ls, z[2] - m - ls, z[3] - m - ls);
}

// ---------------------------------------------------------------------------

extern "C" void kernel_launch(void* const* d_in, const int* in_sizes, int n_in,
                              void* d_out, int out_size, void* d_ws, size_t ws_size,
                              hipStream_t stream) {
    const float* feature = (const float*)d_in[0];
    const int*   src     = (const int*)d_in[1];
    const int*   dst     = (const int*)d_in[2];
    const float* ew      = (const float*)d_in[3];
    const float* W1      = (const float*)d_in[4];
    const float* b1      = (const float*)d_in[5];
    const float* W2      = (const float*)d_in[6];
    const float* b2      = (const float*)d_in[7];

    const int E    = in_sizes[1];
    const int H    = in_sizes[5];            // 128
    const int D    = in_sizes[7];            // 64
    const int F_IN = in_sizes[4] / H;        // 256
    const int N    = in_sizes[0] / F_IN;     // 100000

    float* out_x1 = (float*)d_out;                   // [N, H] fp32
    float* out_x2 = (float*)d_out + (size_t)N * H;   // [N, D] fp32

    char* ws = (char*)d_ws;
    auto carve = [&](size_t bytes) {
        char* p = ws;
        ws += (bytes + 15) & ~(size_t)15;
        return p;
    };
    int*   counts    = (int*)  carve((size_t)N * sizeof(int));
    int*   offs      = (int*)  carve((size_t)(N + 1) * sizeof(int));
    int*   cursor    = (int*)  carve((size_t)N * sizeof(int));
    int*   blockSums = (int*)  carve(4096 * sizeof(int));
    uint2* epack     = (uint2*)carve((size_t)E * sizeof(uint2));
    u16*   W1T       = (u16*)  carve((size_t)H * F_IN * sizeof(u16));
    u16*   W2T       = (u16*)  carve((size_t)D * H * sizeof(u16));
    u16*   supbf     = (u16*)  carve((size_t)N * H * sizeof(u16));
    u16*   x1bf      = (u16*)  carve((size_t)N * H * sizeof(u16));

    const int GB  = (N + 127) / 128;     // gemm1 blocks total
    const int GA  = GB / 2;              // first half (mega0)
    const int GB2 = GB - GA;             // second half (mega1)

    // --- weight prep (must precede any gemm1 block) ---
    tc_k<<<(F_IN * H + H * D + 255) / 256, 256, 0, stream>>>(
        W1, W1T, F_IN, H, W2, W2T, H, D);

    hipMemsetAsync(counts, 0, (size_t)N * sizeof(int), stream);

    // --- mega0: histogram || gemm1a ---
    const int E4 = E / 4;
    const int HB = (E4 + 256) / 256;
    mega0_k<<<HB + GA, 256, 0, stream>>>(
        dst, counts, E4, E, feature, W1T, supbf, N, F_IN, GA);

    // --- scans ---
    const int nScanBlocks = (N + SCAN_TILE - 1) / SCAN_TILE;
    scan_pass1<<<nScanBlocks, SCAN_B, 0, stream>>>(counts, offs, blockSums, N);
    scan_pass2<<<1, 64, 0, stream>>>(blockSums, nScanBlocks);
    scan_pass3<<<(N + 1 + SCAN_B - 1) / SCAN_B, SCAN_B, 0, stream>>>(
        offs, cursor, blockSums, N, E);

    // --- mega1: reorder || gemm1b ---
    {
        const int RB = ((E + EPT - 1) / EPT + 255) / 256;
        mega1_k<<<RB + GB2, 256, 0, stream>>>(
            src, dst, ew, cursor, epack, E,
            feature, W1T, supbf, N, F_IN, GA, GB2);
    }

    // --- agg layer 1 (fused bias+relu, dual output) ---
    agg_f128b<<<(N * 16 + 255) / 256, 256, 0, stream>>>(
        supbf, offs, epack, b1, out_x1, x1bf, N);

    // --- layer 2 ---
    gemm2_k<<<(N + 127) / 128, 256, 0, stream>>>(x1bf, W2T, supbf, N, H);
    agg_f64_lsm<<<(N * 16 + 255) / 256, 256, 0, stream>>>(
        supbf, offs, epack, b2, out_x2, N);
}

// Round 8
// 405.920 us; speedup vs baseline: 10.6551x; 1.2116x over previous
//
#include <hip/hip_runtime.h>
#include <hip/hip_bf16.h>
#include <type_traits>

// ---------------------------------------------------------------------------
// GCN forward, 2 layers. Round 8: atomic-free CSR build via 2-level counting
// sort (all returning atomics moved to LDS; global scatter becomes dense).
//
//  sortA1 (+weight tc): per-block LDS hist over 391 coarse buckets (dst>>8)
//  scan1/scan2/scan3G : flat exclusive scan of G[bucket][block] (76K ints)
//  sortA2             : place edges into bucket-grouped scratch (dense runs)
//  megaB (+gemm1)     : per-bucket exact sort -> offs[] + epack[]; gemm1
//                       blocks interleaved 2:1 by block index
//  agg_f128b          : x1 = relu(sum w*sup1[src]+b1), fp32 out + bf16 copy
//  gemm2              : sup2 = x1bf @ W2
//  agg_f64_lsm        : out2 = log_softmax(sum w*sup2[src]+b2)
// ---------------------------------------------------------------------------

typedef unsigned short u16;
typedef unsigned char  u8;

__device__ __forceinline__ u16 f2bf(float x) {
    union { float f; unsigned u; } v; v.f = x;
    const unsigned r = v.u + 0x7FFFu + ((v.u >> 16) & 1u);   // RNE
    return (u16)(r >> 16);
}
__device__ __forceinline__ float bf2f(unsigned h) {
    union { unsigned u; float f; } v; v.u = h << 16;
    return v.f;
}
__device__ __forceinline__ float uaf(unsigned u) {
    union { unsigned u; float f; } v; v.u = u;
    return v.f;
}
__device__ __forceinline__ unsigned fau(float f) {
    union { float f; unsigned u; } v; v.f = f;
    return v.u;
}

using short8  = __attribute__((ext_vector_type(8))) short;
using float4v = __attribute__((ext_vector_type(4))) float;

#define TILE_A 8192

// ---------------- MFMA GEMM body: C[M,BNt](bf16) = A[M,K] @ BT[BNt,K]^T -----
template <typename AT, int BNt>
__device__ __forceinline__ void gemm_body(
    const int bix, const AT* __restrict__ A, const u16* __restrict__ BT,
    u16* __restrict__ C, const int M, const int K)
{
    constexpr int BMt = 128;
    constexpr int WAVES_N = BNt / 64;
    constexpr int WROWS = 4 / WAVES_N;
    constexpr int WMF = BMt / (16 * WROWS);
    constexpr int WNF = 4;

    __shared__ __align__(16) u16 As[BMt * 32];
    __shared__ __align__(16) u16 Bs[BNt * 32];

    const int tid  = threadIdx.x;
    const int lane = tid & 63;
    const int w    = tid >> 6;
    const int m0   = bix * BMt;

    const int wm = (w % WROWS) * (WMF * 16);
    const int wn = (w / WROWS) * 64;

    const int fm = lane & 15;
    const int kh = lane >> 4;

    float4v acc[WMF][WNF] = {};

    for (int k0 = 0; k0 < K; k0 += 32) {
        __syncthreads();
        if constexpr (std::is_same<AT, float>::value) {
#pragma unroll
            for (int i = 0; i < 4; ++i) {
                const int s   = i * 256 + tid;
                const int row = s >> 3;
                const int seg = s & 7;
                const int gr  = min(m0 + row, M - 1);
                const float4 v = *(const float4*)&A[(size_t)gr * K + k0 + seg * 4];
                ushort4 o;
                o.x = f2bf(v.x); o.y = f2bf(v.y); o.z = f2bf(v.z); o.w = f2bf(v.w);
                *(ushort4*)&As[row * 32 + seg * 4] = o;
            }
        } else {
#pragma unroll
            for (int i = 0; i < 2; ++i) {
                const int s   = i * 256 + tid;
                const int row = s >> 2;
                const int seg = s & 3;
                const int gr  = min(m0 + row, M - 1);
                *(uint4*)&As[row * 32 + seg * 8] =
                    *(const uint4*)&A[(size_t)gr * K + k0 + seg * 8];
            }
        }
#pragma unroll
        for (int i = 0; i < BNt * 4 / 256; ++i) {
            const int s   = i * 256 + tid;
            const int row = s >> 2;
            const int seg = s & 3;
            *(uint4*)&Bs[row * 32 + seg * 8] =
                *(const uint4*)&BT[(size_t)row * K + k0 + seg * 8];
        }
        __syncthreads();

        short8 af[WMF], bfr[WNF];
#pragma unroll
        for (int i = 0; i < WMF; ++i)
            af[i] = *(const short8*)&As[(wm + i * 16 + fm) * 32 + kh * 8];
#pragma unroll
        for (int j = 0; j < WNF; ++j)
            bfr[j] = *(const short8*)&Bs[(wn + j * 16 + fm) * 32 + kh * 8];
#pragma unroll
        for (int i = 0; i < WMF; ++i)
#pragma unroll
            for (int j = 0; j < WNF; ++j)
                acc[i][j] = __builtin_amdgcn_mfma_f32_16x16x32_bf16(
                    af[i], bfr[j], acc[i][j], 0, 0, 0);
    }

#pragma unroll
    for (int i = 0; i < WMF; ++i) {
#pragma unroll
        for (int j = 0; j < WNF; ++j) {
            const int col = wn + j * 16 + fm;
#pragma unroll
            for (int r = 0; r < 4; ++r) {
                const int row = m0 + wm + i * 16 + kh * 4 + r;
                if (row < M) C[(size_t)row * BNt + col] = f2bf(acc[i][j][r]);
            }
        }
    }
}

__global__ __launch_bounds__(256) void gemm2_k(
    const u16* __restrict__ A, const u16* __restrict__ BT,
    u16* __restrict__ C, int M, int K)
{
    gemm_body<u16, 64>(blockIdx.x, A, BT, C, M, K);
}

// ---------------- sort pass A1: per-block coarse histogram (+ weight tc) ----
__global__ __launch_bounds__(256) void sortA1_k(
    const int* __restrict__ dst, int* __restrict__ G, int E, int NBLK, int NB,
    const float* __restrict__ W1, u16* __restrict__ W1T, int K1, int N1,
    const float* __restrict__ W2, u16* __restrict__ W2T, int K2, int N2)
{
    const int b = blockIdx.x;
    if (b >= NBLK) {
        // weight transpose/cast role
        const int t = (b - NBLK) * 256 + threadIdx.x;
        const int tot1 = K1 * N1;
        if (t < tot1) {
            const int k = t % K1, nn = t / K1;
            W1T[(size_t)nn * K1 + k] = f2bf(W1[(size_t)k * N1 + nn]);
        } else {
            const int t2 = t - tot1;
            if (t2 < K2 * N2) {
                const int k = t2 % K2, nn = t2 / K2;
                W2T[(size_t)nn * K2 + k] = f2bf(W2[(size_t)k * N2 + nn]);
            }
        }
        return;
    }

    __shared__ int hist[512];
    for (int i = threadIdx.x; i < NB; i += 256) hist[i] = 0;
    __syncthreads();
    const int base = b * TILE_A;
#pragma unroll 4
    for (int i = 0; i < TILE_A; i += 256) {
        const int e = base + i + threadIdx.x;
        if (e < E) atomicAdd(&hist[((unsigned)dst[e]) >> 8], 1);
    }
    __syncthreads();
    for (int i = threadIdx.x; i < NB; i += 256)
        G[(size_t)i * NBLK + b] = hist[i];
}

// ---------------- scans (over flat G, length NB*NBLK) ----------------

#define SCAN_B 256
#define SCAN_I 8
#define SCAN_TILE (SCAN_B * SCAN_I)   // 2048

__global__ __launch_bounds__(SCAN_B) void scan_pass1(
    const int* __restrict__ in, int* __restrict__ out,
    int* __restrict__ blockSums, int n)
{
    __shared__ int waveSums[SCAN_B / 64];
    const int tid = threadIdx.x;
    const int lane = tid & 63;
    const int wid = tid >> 6;
    const int base = blockIdx.x * SCAN_TILE + tid * SCAN_I;

    int items[SCAN_I];
    int tsum = 0;
#pragma unroll
    for (int i = 0; i < SCAN_I; ++i) {
        const int idx = base + i;
        items[i] = (idx < n) ? in[idx] : 0;
        tsum += items[i];
    }
    int x = tsum;
#pragma unroll
    for (int o = 1; o < 64; o <<= 1) {
        const int y = __shfl_up(x, o, 64);
        if (lane >= o) x += y;
    }
    if (lane == 63) waveSums[wid] = x;
    __syncthreads();
    if (tid == 0) {
        int acc = 0;
#pragma unroll
        for (int w = 0; w < SCAN_B / 64; ++w) {
            const int t = waveSums[w]; waveSums[w] = acc; acc += t;
        }
        blockSums[blockIdx.x] = acc;
    }
    __syncthreads();
    int texcl = x - tsum + waveSums[wid];
#pragma unroll
    for (int i = 0; i < SCAN_I; ++i) {
        const int idx = base + i;
        if (idx < n) out[idx] = texcl;
        texcl += items[i];
    }
}

__global__ void scan_pass2(int* __restrict__ blockSums, int nb)
{
    const int lane = threadIdx.x;
    int run = 0;
    for (int base = 0; base < nb; base += 64) {
        const int idx = base + lane;
        const int v = (idx < nb) ? blockSums[idx] : 0;
        int x = v;
#pragma unroll
        for (int o = 1; o < 64; o <<= 1) {
            const int y = __shfl_up(x, o, 64);
            if (lane >= o) x += y;
        }
        if (idx < nb) blockSums[idx] = run + x - v;
        run += __shfl(x, 63, 64);
    }
}

__global__ __launch_bounds__(SCAN_B) void scan3G_k(
    int* __restrict__ G, const int* __restrict__ blockSums, int n,
    int* __restrict__ offs, int N, int E)
{
    const int idx = blockIdx.x * blockDim.x + threadIdx.x;
    if (idx < n) G[idx] += blockSums[idx / SCAN_TILE];
    if (idx == 0) offs[N] = E;
}

// ---------------- sort pass A2: place into bucket-grouped scratch ----------
__global__ __launch_bounds__(256) void sortA2_k(
    const int* __restrict__ src, const int* __restrict__ dst,
    const float* __restrict__ ew, const int* __restrict__ G,
    uint2* __restrict__ eps, u8* __restrict__ ldst, int E, int NBLK, int NB)
{
    const int b = blockIdx.x;
    __shared__ int cur[512];
    for (int i = threadIdx.x; i < NB; i += 256)
        cur[i] = G[(size_t)i * NBLK + b];
    __syncthreads();
    const int base = b * TILE_A;
#pragma unroll 4
    for (int i = 0; i < TILE_A; i += 256) {
        const int e = base + i + threadIdx.x;
        if (e < E) {
            const int d = dst[e];
            const int p = atomicAdd(&cur[((unsigned)d) >> 8], 1);
            eps[p]  = make_uint2((unsigned)src[e], fau(ew[e]));
            ldst[p] = (u8)(d & 255);
        }
    }
}

// ---------------- megaB: per-bucket exact sort || gemm1 ---------------------
// Block roles: b%3==0 && b/3<SB -> sort bucket b/3; else gemm1 block.
__global__ __launch_bounds__(256) void megaB_k(
    const uint2* __restrict__ eps, const u8* __restrict__ ldst,
    const int* __restrict__ G, int* __restrict__ offs,
    uint2* __restrict__ epack, int E, int NBLK, int NB, int N,
    const float* __restrict__ A, const u16* __restrict__ BT,
    u16* __restrict__ C, int M, int K, int GB)
{
    const int b = blockIdx.x;
    const int third = b / 3;
    int sort_id = -1, gemm_id = -1;
    if ((b % 3) == 0 && third < NB) sort_id = third;
    else gemm_id = b - min((b + 2) / 3, NB);

    if (gemm_id >= 0) {
        if (gemm_id < GB) gemm_body<float, 128>(gemm_id, A, BT, C, M, K);
        return;
    }

    const int tid = threadIdx.x;
    const int sb = sort_id;
    const int start = G[(size_t)sb * NBLK];
    const int endv  = (sb + 1 < NB) ? G[(size_t)(sb + 1) * NBLK] : E;

    __shared__ int h[256];
    __shared__ int wsum[4];
    h[tid] = 0;
    __syncthreads();
    for (int i = start + tid; i < endv; i += 256)
        atomicAdd(&h[ldst[i]], 1);
    __syncthreads();

    // 256-entry exclusive scan (wave shfl + 4-way combine)
    const int lane = tid & 63;
    const int w = tid >> 6;
    const int v = h[tid];
    int x = v;
#pragma unroll
    for (int o = 1; o < 64; o <<= 1) {
        const int y = __shfl_up(x, o, 64);
        if (lane >= o) x += y;
    }
    if (lane == 63) wsum[w] = x;
    __syncthreads();
    if (tid == 0) {
        int a = 0;
#pragma unroll
        for (int q = 0; q < 4; ++q) { const int t = wsum[q]; wsum[q] = a; a += t; }
    }
    __syncthreads();
    const int excl = start + (x - v) + wsum[w];

    const int node = sb * 256 + tid;
    if (node < N) offs[node] = excl;

    __syncthreads();
    h[tid] = excl;          // reuse as per-node cursor
    __syncthreads();

    for (int i = start + tid; i < endv; i += 256) {
        const uint2 ep = eps[i];
        const int p = atomicAdd(&h[ldst[i]], 1);
        epack[p] = ep;
    }
}

// ---------------- gather-side aggregation (bf16 payload) ----------------
// 4 nodes per wave: 16 lanes per node, 16B (8 bf16) per lane.

__global__ __launch_bounds__(256) void agg_f128b(
    const u16* __restrict__ sup, const int* __restrict__ offs,
    const uint2* __restrict__ epack, const float* __restrict__ bias,
    float* __restrict__ out, u16* __restrict__ out_bf, int N)
{
    const int node = (blockIdx.x * blockDim.x + threadIdx.x) >> 4;
    const int hl = threadIdx.x & 15;
    if (node >= N) return;

    const int beg = offs[node];
    const int end = offs[node + 1];

    float a[2][8] = {};
    int j = beg;
    for (; j + 7 < end; j += 8) {
        uint2 e[8];
#pragma unroll
        for (int i = 0; i < 8; ++i) e[i] = epack[j + i];
        uint4 v[8];
#pragma unroll
        for (int i = 0; i < 8; ++i)
            v[i] = *(const uint4*)&sup[(size_t)e[i].x * 128 + hl * 8];
#pragma unroll
        for (int i = 0; i < 8; ++i) {
            const float w = uaf(e[i].y);
            float* acc = a[i & 1];
            acc[0] = fmaf(bf2f(v[i].x & 0xffffu), w, acc[0]);
            acc[1] = fmaf(bf2f(v[i].x >> 16),     w, acc[1]);
            acc[2] = fmaf(bf2f(v[i].y & 0xffffu), w, acc[2]);
            acc[3] = fmaf(bf2f(v[i].y >> 16),     w, acc[3]);
            acc[4] = fmaf(bf2f(v[i].z & 0xffffu), w, acc[4]);
            acc[5] = fmaf(bf2f(v[i].z >> 16),     w, acc[5]);
            acc[6] = fmaf(bf2f(v[i].w & 0xffffu), w, acc[6]);
            acc[7] = fmaf(bf2f(v[i].w >> 16),     w, acc[7]);
        }
    }
    for (; j < end; ++j) {
        const uint2 e0 = epack[j];
        const float w = uaf(e0.y);
        const uint4 v0 = *(const uint4*)&sup[(size_t)e0.x * 128 + hl * 8];
        a[0][0] = fmaf(bf2f(v0.x & 0xffffu), w, a[0][0]);
        a[0][1] = fmaf(bf2f(v0.x >> 16),     w, a[0][1]);
        a[0][2] = fmaf(bf2f(v0.y & 0xffffu), w, a[0][2]);
        a[0][3] = fmaf(bf2f(v0.y >> 16),     w, a[0][3]);
        a[0][4] = fmaf(bf2f(v0.z & 0xffffu), w, a[0][4]);
        a[0][5] = fmaf(bf2f(v0.z >> 16),     w, a[0][5]);
        a[0][6] = fmaf(bf2f(v0.w & 0xffffu), w, a[0][6]);
        a[0][7] = fmaf(bf2f(v0.w >> 16),     w, a[0][7]);
    }
    const float4 b0 = *(const float4*)&bias[hl * 8];
    const float4 b1 = *(const float4*)&bias[hl * 8 + 4];
    float o[8];
    o[0] = fmaxf(a[0][0] + a[1][0] + b0.x, 0.f);
    o[1] = fmaxf(a[0][1] + a[1][1] + b0.y, 0.f);
    o[2] = fmaxf(a[0][2] + a[1][2] + b0.z, 0.f);
    o[3] = fmaxf(a[0][3] + a[1][3] + b0.w, 0.f);
    o[4] = fmaxf(a[0][4] + a[1][4] + b1.x, 0.f);
    o[5] = fmaxf(a[0][5] + a[1][5] + b1.y, 0.f);
    o[6] = fmaxf(a[0][6] + a[1][6] + b1.z, 0.f);
    o[7] = fmaxf(a[0][7] + a[1][7] + b1.w, 0.f);
    float* orow = &out[(size_t)node * 128 + hl * 8];
    *(float4*)&orow[0] = make_float4(o[0], o[1], o[2], o[3]);
    *(float4*)&orow[4] = make_float4(o[4], o[5], o[6], o[7]);
    uint4 pb;
    pb.x = (unsigned)f2bf(o[0]) | ((unsigned)f2bf(o[1]) << 16);
    pb.y = (unsigned)f2bf(o[2]) | ((unsigned)f2bf(o[3]) << 16);
    pb.z = (unsigned)f2bf(o[4]) | ((unsigned)f2bf(o[5]) << 16);
    pb.w = (unsigned)f2bf(o[6]) | ((unsigned)f2bf(o[7]) << 16);
    *(uint4*)&out_bf[(size_t)node * 128 + hl * 8] = pb;
}

__global__ __launch_bounds__(256) void agg_f64_lsm(
    const u16* __restrict__ sup, const int* __restrict__ offs,
    const uint2* __restrict__ epack, const float* __restrict__ bias,
    float* __restrict__ out, int N)
{
    const int node = (blockIdx.x * blockDim.x + threadIdx.x) >> 4;
    const int hl = threadIdx.x & 15;
    if (node >= N) return;

    const int beg = offs[node];
    const int end = offs[node + 1];

    float a[2][4] = {};
    int j = beg;
    for (; j + 7 < end; j += 8) {
        uint2 e[8];
#pragma unroll
        for (int i = 0; i < 8; ++i) e[i] = epack[j + i];
        uint2 v[8];
#pragma unroll
        for (int i = 0; i < 8; ++i)
            v[i] = *(const uint2*)&sup[(size_t)e[i].x * 64 + hl * 4];
#pragma unroll
        for (int i = 0; i < 8; ++i) {
            const float w = uaf(e[i].y);
            float* acc = a[i & 1];
            acc[0] = fmaf(bf2f(v[i].x & 0xffffu), w, acc[0]);
            acc[1] = fmaf(bf2f(v[i].x >> 16),     w, acc[1]);
            acc[2] = fmaf(bf2f(v[i].y & 0xffffu), w, acc[2]);
            acc[3] = fmaf(bf2f(v[i].y >> 16),     w, acc[3]);
        }
    }
    for (; j < end; ++j) {
        const uint2 e0 = epack[j];
        const float w = uaf(e0.y);
        const uint2 v0 = *(const uint2*)&sup[(size_t)e0.x * 64 + hl * 4];
        a[0][0] = fmaf(bf2f(v0.x & 0xffffu), w, a[0][0]);
        a[0][1] = fmaf(bf2f(v0.x >> 16),     w, a[0][1]);
        a[0][2] = fmaf(bf2f(v0.y & 0xffffu), w, a[0][2]);
        a[0][3] = fmaf(bf2f(v0.y >> 16),     w, a[0][3]);
    }

    const float4 b4 = *(const float4*)&bias[hl * 4];
    float z[4];
    z[0] = a[0][0] + a[1][0] + b4.x;
    z[1] = a[0][1] + a[1][1] + b4.y;
    z[2] = a[0][2] + a[1][2] + b4.z;
    z[3] = a[0][3] + a[1][3] + b4.w;

    float m = fmaxf(fmaxf(z[0], z[1]), fmaxf(z[2], z[3]));
#pragma unroll
    for (int o = 8; o > 0; o >>= 1) m = fmaxf(m, __shfl_xor(m, o, 64));
    float s = __expf(z[0] - m) + __expf(z[1] - m) + __expf(z[2] - m) + __expf(z[3] - m);
#pragma unroll
    for (int o = 8; o > 0; o >>= 1) s += __shfl_xor(s, o, 64);
    const float ls = __logf(s);
    *(float4*)&out[(size_t)node * 64 + hl * 4] =
        make_float4(z[0] - m - ls, z[1] - m - ls, z[2] - m - ls, z[3] - m - ls);
}

// ---------------------------------------------------------------------------

extern "C" void kernel_launch(void* const* d_in, const int* in_sizes, int n_in,
                              void* d_out, int out_size, void* d_ws, size_t ws_size,
                              hipStream_t stream) {
    const float* feature = (const float*)d_in[0];
    const int*   src     = (const int*)d_in[1];
    const int*   dst     = (const int*)d_in[2];
    const float* ew      = (const float*)d_in[3];
    const float* W1      = (const float*)d_in[4];
    const float* b1      = (const float*)d_in[5];
    const float* W2      = (const float*)d_in[6];
    const float* b2      = (const float*)d_in[7];

    const int E    = in_sizes[1];
    const int H    = in_sizes[5];            // 128
    const int D    = in_sizes[7];            // 64
    const int F_IN = in_sizes[4] / H;        // 256
    const int N    = in_sizes[0] / F_IN;     // 100000

    float* out_x1 = (float*)d_out;                   // [N, H] fp32
    float* out_x2 = (float*)d_out + (size_t)N * H;   // [N, D] fp32

    const int NB   = (N + 255) >> 8;         // coarse buckets (391)
    const int NBLK = (E + TILE_A - 1) / TILE_A;  // A-blocks (196)
    const int nG   = NB * NBLK;              // flat G length
    const int GB   = (N + 127) / 128;        // gemm1 blocks

    char* ws = (char*)d_ws;
    auto carve = [&](size_t bytes) {
        char* p = ws;
        ws += (bytes + 15) & ~(size_t)15;
        return p;
    };
    int*   G         = (int*)  carve((size_t)nG * sizeof(int));
    int*   blockSums = (int*)  carve(4096 * sizeof(int));
    int*   offs      = (int*)  carve((size_t)(N + 1) * sizeof(int));
    uint2* epack     = (uint2*)carve((size_t)E * sizeof(uint2));
    u16*   W1T       = (u16*)  carve((size_t)H * F_IN * sizeof(u16));
    u16*   W2T       = (u16*)  carve((size_t)D * H * sizeof(u16));
    u16*   supbf     = (u16*)  carve((size_t)N * H * sizeof(u16));
    u16*   x1bf      = (u16*)  carve((size_t)N * H * sizeof(u16));
    // eps/ldst scratch aliased onto x1bf (dead before agg_f128b writes x1bf):
    // need E*8 + E <= N*H*2  (14.4MB <= 25.6MB) -- holds.
    uint2* eps  = (uint2*)x1bf;
    u8*    ldst = (u8*)x1bf + (size_t)E * sizeof(uint2);

    // --- A1: coarse histogram + weight transposes ---
    {
        const int TCB = (F_IN * H + H * D + 255) / 256;
        sortA1_k<<<NBLK + TCB, 256, 0, stream>>>(
            dst, G, E, NBLK, NB, W1, W1T, F_IN, H, W2, W2T, H, D);
    }

    // --- scan of G (flat, bucket-major) ---
    const int nScanBlocks = (nG + SCAN_TILE - 1) / SCAN_TILE;
    scan_pass1<<<nScanBlocks, SCAN_B, 0, stream>>>(G, G, blockSums, nG);
    scan_pass2<<<1, 64, 0, stream>>>(blockSums, nScanBlocks);
    scan3G_k<<<(nG + SCAN_B - 1) / SCAN_B, SCAN_B, 0, stream>>>(
        G, blockSums, nG, offs, N, E);

    // --- A2: dense bucket-grouped placement ---
    sortA2_k<<<NBLK, 256, 0, stream>>>(src, dst, ew, G, eps, ldst, E, NBLK, NB);

    // --- megaB: per-bucket exact sort || gemm1 ---
    {
        int grid = NB + GB;
        if (grid < 3 * NB - 2) grid = 3 * NB - 2;   // ensure all sort blocks exist
        megaB_k<<<grid, 256, 0, stream>>>(
            eps, ldst, G, offs, epack, E, NBLK, NB, N,
            feature, W1T, supbf, N, F_IN, GB);
    }

    // --- agg layer 1 (fused bias+relu, dual output) ---
    agg_f128b<<<(N * 16 + 255) / 256, 256, 0, stream>>>(
        supbf, offs, epack, b1, out_x1, x1bf, N);

    // --- layer 2 ---
    gemm2_k<<<(N + 127) / 128, 256, 0, stream>>>(x1bf, W2T, supbf, N, H);
    agg_f64_lsm<<<(N * 16 + 255) / 256, 256, 0, stream>>>(
        supbf, offs, epack, b2, out_x2, N);
}